// Round 1
// baseline (1416.202 us; speedup 1.0000x reference)
//
#include <hip/hip_runtime.h>

#define BS   256
#define HID  1024
#define KIN  8000
#define TST  100
#define ACTD 32
#define OUTD 64
#define KTOT 1056            // 1024 (Wh) + 32 (Wi) concatenated K
#define WP   1104            // Wlds row pitch in halfs (552 dw, %32==8 -> uniform banks)
#define HEXCH (16 * 32 * 512)  // one h buffer: 16 rgrp x 32 kb x 512 u16 (512 KB)

typedef __attribute__((ext_vector_type(8))) _Float16 f16x8;
typedef __attribute__((ext_vector_type(4))) float f32x4;
typedef unsigned short u16;
typedef unsigned int   u32;
typedef unsigned long long u64;

__device__ __forceinline__ u16 f2h(float f) {
    union { _Float16 h; u16 u; } c;
    c.h = (_Float16)f;             // v_cvt_f16_f32, RNE
    return c.u;
}
// fast sigmoid/tanh: v_exp + v_rcp (no fp32 div sequence, no libm tanhf).
// tanh via -2|x| so exp underflows (never overflows) -> no NaN path.
__device__ __forceinline__ float sigm(float x) {
    return __builtin_amdgcn_rcpf(1.0f + __expf(-x));
}
__device__ __forceinline__ float tanh_fast(float x) {
    float e = __expf(-2.0f * fabsf(x));
    float t = (1.0f - e) * __builtin_amdgcn_rcpf(1.0f + e);
    return copysignf(t, x);
}

#define MFMA16(a, b, c) __builtin_amdgcn_mfma_f32_16x16x32_f16(a, b, c, 0, 0, 0)

// Memory-side coherent 16B load (two relaxed agent-scope u64 atomics).
__device__ __forceinline__ f16x8 aload(const u16* p) {
    union { u64 d[2]; f16x8 v; } u;
    const u64* q = (const u64*)(const void*)p;
    u.d[0] = __hip_atomic_load(q + 0, __ATOMIC_RELAXED, __HIP_MEMORY_SCOPE_AGENT);
    u.d[1] = __hip_atomic_load(q + 1, __ATOMIC_RELAXED, __HIP_MEMORY_SCOPE_AGENT);
    return u.v;
}

// ---------------- P1: WfT[c][k] = fp16(Wh[k][c] | Wi[k-1024][c]) ----------------
__global__ __launch_bounds__(256) void k_prep_w(const float* __restrict__ Wh,
                                                const float* __restrict__ Wi,
                                                u16* __restrict__ Wf) {
    __shared__ float T[32][33];
    const int k0 = blockIdx.x * 32;      // 33 tiles cover k=0..1055
    const int c0 = blockIdx.y * 32;
    const int tid = threadIdx.x;
    {
        int k = tid >> 3, c4 = (tid & 7) * 4;
        int kk = k0 + k;
        const float* src = (kk < HID) ? (Wh + (size_t)kk * 3072 + c0 + c4)
                                      : (Wi + (size_t)(kk - HID) * 3072 + c0 + c4);
        float4 v = *(const float4*)src;
        T[k][c4 + 0] = v.x; T[k][c4 + 1] = v.y; T[k][c4 + 2] = v.z; T[k][c4 + 3] = v.w;
    }
    __syncthreads();
    {
        int c = tid >> 3, k4 = (tid & 7) * 4;
        size_t base = (size_t)(c0 + c) * KTOT + k0 + k4;
#pragma unroll
        for (int j = 0; j < 4; j++) Wf[base + j] = f2h(T[k4 + j][c]);
    }
}

// ---------------- P2: WoT[n][k] = fp16(Wo[k][n]) ----------------
__global__ __launch_bounds__(256) void k_prep_wo(const float* __restrict__ Wo,
                                                 u16* __restrict__ WoT) {
    int idx = blockIdx.x * 256 + threadIdx.x;   // 65536
    int n = idx & 63, k = idx >> 6;
    WoT[(size_t)n * HID + k] = f2h(Wo[(size_t)k * OUTD + n]);
}

// ---------------- P3: action fp32 -> fp16 (layout preserved) ----------------
__global__ __launch_bounds__(256) void k_prep_act(const float* __restrict__ act,
                                                  u16* __restrict__ acth) {
    int i = (blockIdx.x * 256 + threadIdx.x) * 4;
    float4 v = *(const float4*)(act + i);
    ushort4 h = make_ushort4(f2h(v.x), f2h(v.y), f2h(v.z), f2h(v.w));
    *(ushort4*)(acth + i) = h;
}

// ---------------- h0 partial GEMM (fp32, split-K) ----------------
#define H0_SPLIT 10
#define H0_KC    800
__global__ __launch_bounds__(256) void k_h0(const float* __restrict__ x,
                                            const float* __restrict__ Win,
                                            float* __restrict__ part) {
    __shared__ float As[32][33];   // [k][m]
    __shared__ float Bs[32][68];   // [k][n]
    const int n0 = blockIdx.x * 64, m0 = blockIdx.y * 32, s = blockIdx.z;
    const int tid = threadIdx.x;
    const int tm = tid >> 4, tn = tid & 15;
    float acc[2][4] = {};

    const int ar = tid >> 3, ac4 = (tid & 7) * 4;
    int br[2], bn4[2];
#pragma unroll
    for (int i = 0; i < 2; i++) { int e = tid + 256 * i; br[i] = e >> 4; bn4[i] = (e & 15) * 4; }
    const int k0 = s * H0_KC;

    float4 aReg = *(const float4*)(x + (size_t)(m0 + ar) * KIN + k0 + ac4);
    float4 bReg0 = *(const float4*)(Win + (size_t)(k0 + br[0]) * HID + n0 + bn4[0]);
    float4 bReg1 = *(const float4*)(Win + (size_t)(k0 + br[1]) * HID + n0 + bn4[1]);

    for (int it = 0; it < 25; it++) {
        __syncthreads();
        As[ac4 + 0][ar] = aReg.x; As[ac4 + 1][ar] = aReg.y;
        As[ac4 + 2][ar] = aReg.z; As[ac4 + 3][ar] = aReg.w;
        *(float4*)&Bs[br[0]][bn4[0]] = bReg0;
        *(float4*)&Bs[br[1]][bn4[1]] = bReg1;
        if (it < 24) {
            int kn = k0 + (it + 1) * 32;
            aReg  = *(const float4*)(x + (size_t)(m0 + ar) * KIN + kn + ac4);
            bReg0 = *(const float4*)(Win + (size_t)(kn + br[0]) * HID + n0 + bn4[0]);
            bReg1 = *(const float4*)(Win + (size_t)(kn + br[1]) * HID + n0 + bn4[1]);
        }
        __syncthreads();
#pragma unroll
        for (int kk = 0; kk < 32; kk++) {
            float a0 = As[kk][tm * 2], a1 = As[kk][tm * 2 + 1];
            float4 b = *(float4*)&Bs[kk][tn * 4];
            acc[0][0] = fmaf(a0, b.x, acc[0][0]); acc[0][1] = fmaf(a0, b.y, acc[0][1]);
            acc[0][2] = fmaf(a0, b.z, acc[0][2]); acc[0][3] = fmaf(a0, b.w, acc[0][3]);
            acc[1][0] = fmaf(a1, b.x, acc[1][0]); acc[1][1] = fmaf(a1, b.y, acc[1][1]);
            acc[1][2] = fmaf(a1, b.z, acc[1][2]); acc[1][3] = fmaf(a1, b.w, acc[1][3]);
        }
    }
    float* dst = part + (size_t)s * (BS * HID);
#pragma unroll
    for (int i = 0; i < 2; i++) {
        float4 v = make_float4(acc[i][0], acc[i][1], acc[i][2], acc[i][3]);
        *(float4*)(dst + (size_t)(m0 + tm * 2 + i) * HID + n0 + tn * 4) = v;
    }
}

// reduce partials; write fp32 h0 and fragment-order fp16 h0 into hfrag buf 0.
__global__ __launch_bounds__(256) void k_h0red(const float* __restrict__ part,
                                               const float* __restrict__ b_in,
                                               float* __restrict__ h0,
                                               u16* __restrict__ hfrag) {
    int idx = (blockIdx.x * 256 + threadIdx.x) * 4;
    float4 sv = *(const float4*)(part + idx);
#pragma unroll
    for (int p = 1; p < H0_SPLIT; p++) {
        float4 v = *(const float4*)(part + (size_t)p * (BS * HID) + idx);
        sv.x += v.x; sv.y += v.y; sv.z += v.z; sv.w += v.w;
    }
    int n = idx & (HID - 1);
    float4 b = *(const float4*)(b_in + n);
    sv.x = fmaxf(sv.x + b.x, 0.f); sv.y = fmaxf(sv.y + b.y, 0.f);
    sv.z = fmaxf(sv.z + b.z, 0.f); sv.w = fmaxf(sv.w + b.w, 0.f);
    *(float4*)(h0 + idx) = sv;
    int row = idx >> 10;
    float vv[4] = {sv.x, sv.y, sv.z, sv.w};
#pragma unroll
    for (int i = 0; i < 4; i++) {
        int c = n + i;
        int lane = ((c & 31) >> 3) * 16 + (row & 15);
        size_t off = ((size_t)(row >> 4) * 32 + (c >> 5)) * 512 + lane * 8 + (c & 7);
        __hip_atomic_store(hfrag + off, f2h(vv[i]), __ATOMIC_RELAXED, __HIP_MEMORY_SCOPE_AGENT);
    }
}

// ---------------- persistent GRU: all 100 steps in one cooperative launch ----------------
// 256 blocks x 512 thr. Block = 16 j-cols x 64 b-rows; bx: j0=(bx>>2)*16, bt=bx&3.
// Weights in LDS once. h exchange in fragment order (dense 1KB chunks).
// R10 changes vs R9:
//  (a) hfrag is now 101 per-step buffers; the exchange store IS the output
//      (k_out consumes fragment order) -> the 1024 scattered 2B outs-stores per
//      block per step are GONE from the pre-barrier drain.
//  (b) barrier thinned: only wave 3 does the dense 2KB store + waitcnt + add;
//      all other waves poll the group counter directly (no barrier syncthreads,
//      no drain for 7/8 waves). Safety: RED(t+1) writes happen only after
//      poll(t) passes, which needs our wave-3 add, which is after sync#2(t),
//      which is after all RED(t)/HST(t) reads.
//  (c) tanh/sigmoid via v_exp+v_rcp (critical kq==0 wave shortens).
__global__ __launch_bounds__(512, 1) void k_gru(const float* __restrict__ h0f,
                                                const u16* __restrict__ acth,
                                                const u16* __restrict__ Wf,
                                                const float* __restrict__ bi,
                                                const float* __restrict__ bhn,
                                                u16* __restrict__ hfrag,
                                                u32* __restrict__ bars) {
    __shared__ u16 Wlds[3 * 16 * WP];          // 106 KB
    __shared__ float RED[2 * 3 * 2 * 64 * 17]; // 52.2 KB, pitch 17 = conflict-free
    __shared__ u16 HST[4 * 256];               // 2 KB h-store staging (rgidx x 256 u16)

    const int tid = threadIdx.x;
    const int bx = blockIdx.x;
    const int j0 = (bx >> 2) * 16;
    const int bt = bx & 3;
    const int b0 = bt * 64;
    const int w = tid >> 6;
    const int bsup = w >> 2, kq = w & 3;
    const int lane = tid & 63;
    const int m16 = lane & 15, quad = lane >> 4;

    // ---- stage weight slice to LDS (once) ----
    for (int p = 0; p < 13; p++) {
        int c = tid + p * 512;                 // 6336 chunks of 8 halfs
        if (c < 6336) {
            int row = c / 132, kc = (c % 132) * 8;
            int g = row >> 4, jj = row & 15;
            int4 v = *(const int4*)(const void*)(Wf + (size_t)(g * HID + j0 + jj) * KTOT + kc);
            *(int4*)(void*)&Wlds[row * WP + kc] = v;
        }
    }

    // home-wave persistent state
    const int j = j0 + m16;
    float bir = 0, biz = 0, bin_ = 0, bh_ = 0;
    float hreg[2][4] = {};
    if (kq == 0) {
        bir = bi[j]; biz = bi[HID + j]; bin_ = bi[2 * HID + j]; bh_ = bhn[j];
#pragma unroll
        for (int sub = 0; sub < 2; sub++)
#pragma unroll
            for (int rg = 0; rg < 4; rg++)
                hreg[sub][rg] = h0f[(size_t)(b0 + bsup * 32 + sub * 16 + quad * 4 + rg) * HID + j];
    }
    __syncthreads();

    const int kst = kq * 256 + (kq ? 32 : 0);  // {0,288,544,800}
    const int iters = kq ? 8 : 9;
    const int kb0 = kst >> 5;                  // {0,9,17,25}
    const int koff = quad * 8;
    const int rgb = b0 >> 4;                   // block's first rgrp
    const int rgrp0 = rgb + bsup * 2;          // this wave's A rgrp (sub0)
    const int row0 = b0 + bsup * 32 + m16;
    const u16* wbr = &Wlds[(0 * 16 + m16) * WP];
    const u16* wbz = &Wlds[(1 * 16 + m16) * WP];
    const u16* wbn = &Wlds[(2 * 16 + m16) * WP];
    const int jb = j0 >> 5;                    // k-chunk col index of this j-tile
    const int halfbase = (j0 & 16) ? 256 : 0;  // u16 offset of our 512B half-chunk
    u32* ctr = bars + bt * 32;                 // 128B-strided group counters

    for (int t = 0; t < TST; t++) {
        const u16* pbase = hfrag + (size_t)t * HEXCH;
        u16* nbase = hfrag + (size_t)(t + 1) * HEXCH;
        const u16* actp0 = acth + (size_t)row0 * (TST * ACTD) + t * ACTD + koff;
        const u16* actp1 = actp0 + 16 * (TST * ACTD);

        // ---- PROLOGUE: issue ALL A-loads back-to-back (latency overlap) ----
        f16x8 a0s[9], a1s[9];
#pragma unroll
        for (int kt = 0; kt < 9; kt++) {
            if (kt < iters) {
                if (kq == 3 && kt == 7) {      // action block (read-only, cached)
                    a0s[kt] = *(const f16x8*)(const void*)actp0;
                    a1s[kt] = *(const f16x8*)(const void*)actp1;
                } else {                       // dense 1KB fragment chunks, uncached
                    const int kb = kb0 + kt;
                    a0s[kt] = aload(pbase + ((size_t)(rgrp0 * 32 + kb) << 9) + lane * 8);
                    a1s[kt] = aload(pbase + ((size_t)((rgrp0 + 1) * 32 + kb) << 9) + lane * 8);
                }
            }
        }

        f32x4 aR[2] = {{0,0,0,0},{0,0,0,0}}, aZ[2] = {{0,0,0,0},{0,0,0,0}};
        f32x4 aN[2] = {{0,0,0,0},{0,0,0,0}}, aI[2] = {{0,0,0,0},{0,0,0,0}};

#pragma unroll
        for (int kt = 0; kt < 9; kt++) {
            if (kt < iters) {
                const int k = kst + kt * 32;
                f16x8 a0 = a0s[kt], a1 = a1s[kt];
                f16x8 wr = *(const f16x8*)&wbr[k + koff];
                f16x8 wz = *(const f16x8*)&wbz[k + koff];
                f16x8 wn = *(const f16x8*)&wbn[k + koff];
                aR[0] = MFMA16(a0, wr, aR[0]);  aR[1] = MFMA16(a1, wr, aR[1]);
                aZ[0] = MFMA16(a0, wz, aZ[0]);  aZ[1] = MFMA16(a1, wz, aZ[1]);
                if (kq == 3 && kt == 7) {
                    aI[0] = MFMA16(a0, wn, aI[0]);  aI[1] = MFMA16(a1, wn, aI[1]);
                } else {
                    aN[0] = MFMA16(a0, wn, aN[0]);  aN[1] = MFMA16(a1, wn, aN[1]);
                }
            }
        }

        if (kq != 0) {
#pragma unroll
            for (int sub = 0; sub < 2; sub++) {
                float* d = &RED[(((bsup * 3 + (kq - 1)) * 2 + sub) * 64 + lane) * 17];
#pragma unroll
                for (int i = 0; i < 4; i++) {
                    d[i]      = aR[sub][i];
                    d[4 + i]  = aZ[sub][i];
                    d[8 + i]  = aN[sub][i];
                    d[12 + i] = aI[sub][i];
                }
            }
        }
        __syncthreads();                       // sync#1
        if (kq == 0) {
#pragma unroll
            for (int sub = 0; sub < 2; sub++) {
                float R[4], Z[4], N[4], I[4];
#pragma unroll
                for (int rg = 0; rg < 4; rg++) {
                    R[rg] = aR[sub][rg]; Z[rg] = aZ[sub][rg];
                    N[rg] = aN[sub][rg]; I[rg] = aI[sub][rg];
                }
#pragma unroll
                for (int src = 0; src < 3; src++) {
                    const float* d = &RED[(((bsup * 3 + src) * 2 + sub) * 64 + lane) * 17];
#pragma unroll
                    for (int rg = 0; rg < 4; rg++) {
                        R[rg] += d[rg]; Z[rg] += d[4 + rg];
                        N[rg] += d[8 + rg]; I[rg] += d[12 + rg];
                    }
                }
                const int rgidx = bsup * 2 + sub;
                const int lh = ((j & 15) >> 3) * 16 + quad * 4;   // lane-in-half base
#pragma unroll
                for (int rg = 0; rg < 4; rg++) {
                    float r = sigm(R[rg] + bir);
                    float z = sigm(Z[rg] + biz);
                    float n = tanh_fast(I[rg] + bin_ + r * (N[rg] + bh_));
                    float hnew = (1.0f - z) * n + z * hreg[sub][rg];
                    hreg[sub][rg] = hnew;
                    HST[rgidx * 256 + (lh + rg) * 8 + (j & 7)] = f2h(hnew);  // LDS scatter
                }
            }
        }
        __syncthreads();                       // sync#2 (HST ready, RED reads done)

        // ---- single-wave dense h store (2 KB) + counter add; others poll ----
        if (w == 3) {
#pragma unroll
            for (int p = 0; p < 4; p++) {
                u64 v = *(const u64*)(const void*)&HST[p * 256 + lane * 4];
                u64* dst = (u64*)(void*)(nbase + (((size_t)(rgb + p) * 32 + jb) << 9)
                                         + halfbase + lane * 4);
                __hip_atomic_store(dst, v, __ATOMIC_RELAXED, __HIP_MEMORY_SCOPE_AGENT);
            }
            if (t < TST - 1) {
                __builtin_amdgcn_s_waitcnt(0); // our exchange stores acked
                if (lane == 0)
                    __hip_atomic_fetch_add(ctr, 1u, __ATOMIC_RELAXED, __HIP_MEMORY_SCOPE_AGENT);
            }
        }
        if (t < TST - 1) {
            u32 tgt = 64u * (u32)(t + 1);
            while (__hip_atomic_load(ctr, __ATOMIC_RELAXED, __HIP_MEMORY_SCOPE_AGENT) < tgt)
                __builtin_amdgcn_s_sleep(1);
        }
        // final step: stores drain at kernel end; next kernel acquires caches.
    }
}

// ---------------- k_out: out[b][t][:] = h_{t+1}[b] @ Wo + bo ----------------
// A comes straight from the fragment-order h buffers: chunk (t+1, rgrp, kb)
// holds the exact MFMA A-fragment (lane = kq*16 + row, 8 k-elems). No LDS.
__global__ __launch_bounds__(256) void k_out(const u16* __restrict__ hfrag,
                                             const u16* __restrict__ WoT,
                                             const float* __restrict__ bo,
                                             float* __restrict__ out) {
    const int tid = threadIdx.x;
    const int t = blockIdx.x % TST;            // 0..99
    const int rg4 = blockIdx.x / TST;          // 0..3
    const int w = tid >> 6, lane = tid & 63;
    const int m16 = lane & 15, quad = lane >> 4;
    const int rgrp = rg4 * 4 + w;              // 0..15 (16 batch rows each)

    const u16* abase = hfrag + (size_t)(t + 1) * HEXCH
                     + (((size_t)rgrp * 32) << 9) + lane * 8;
    const u16* bbase = WoT + (size_t)m16 * HID + quad * 8;
    f32x4 acc[4] = {{0,0,0,0},{0,0,0,0},{0,0,0,0},{0,0,0,0}};

#pragma unroll 4
    for (int kb = 0; kb < 32; kb++) {
        f16x8 a = *(const f16x8*)(const void*)(abase + (kb << 9));
        const u16* bp = bbase + kb * 32;
#pragma unroll
        for (int nt = 0; nt < 4; nt++) {
            f16x8 b = *(const f16x8*)(const void*)(bp + (size_t)nt * 16 * HID);
            acc[nt] = __builtin_amdgcn_mfma_f32_16x16x32_f16(a, b, acc[nt], 0, 0, 0);
        }
    }
    const int brow = rgrp * 16 + quad * 4;     // C layout: col=lane&15, row=quad*4+reg
#pragma unroll
    for (int nt = 0; nt < 4; nt++) {
        int n = nt * 16 + m16;
        float bov = bo[n];
#pragma unroll
        for (int rg = 0; rg < 4; rg++) {
            int b = brow + rg;
            out[((size_t)b * TST + t) * OUTD + n] = acc[nt][rg] + bov;
        }
    }
}

extern "C" void kernel_launch(void* const* d_in, const int* in_sizes, int n_in,
                              void* d_out, int out_size, void* d_ws, size_t ws_size,
                              hipStream_t stream) {
    const float* history = (const float*)d_in[0];
    const float* action  = (const float*)d_in[1];
    const float* W_in    = (const float*)d_in[2];
    const float* b_in    = (const float*)d_in[3];
    const float* Wi      = (const float*)d_in[4];
    const float* bi      = (const float*)d_in[5];
    const float* Wh      = (const float*)d_in[6];
    const float* bhn     = (const float*)d_in[7];
    const float* Wo      = (const float*)d_in[8];
    const float* bo      = (const float*)d_in[9];
    float* out = (float*)d_out;

    char* ws = (char*)d_ws;
    float* hbuf0 = (float*)(ws + 0);                    // 1 MB (fp32 h0)
    u16*   Wf    = (u16*)  (ws + (3u << 20));           // 6.33 MB
    u16*   WoT   = (u16*)  (ws + (10u << 20));          // 128 KB
    u16*   acth  = (u16*)  (ws + (11u << 20));          // 1.6 MB
    float* part  = (float*)(ws + (13u << 20));          // 10 MB (13..23 MiB)
    u32*   bars  = (u32*)  (ws + (23u << 20));          // 512 B group counters
    u16*   hfrag = (u16*)  (ws + (24u << 20));          // 101 x 512 KB = 50.5 MB

    (void)hipMemsetAsync(bars, 0, 512, stream);
    k_prep_w<<<dim3(33, 96), 256, 0, stream>>>(Wh, Wi, Wf);
    k_prep_wo<<<256, 256, 0, stream>>>(Wo, WoT);
    k_prep_act<<<800, 256, 0, stream>>>(action, acth);
    k_h0<<<dim3(16, 8, H0_SPLIT), 256, 0, stream>>>(history, W_in, part);
    k_h0red<<<256, 256, 0, stream>>>(part, b_in, hbuf0, hfrag);

    {
        const float* a0 = hbuf0; const u16* a1 = acth; const u16* a2 = Wf;
        const float* a3 = bi;    const float* a4 = bhn;
        u16* a5 = hfrag;         u32* a6 = bars;
        void* args[] = {(void*)&a0, (void*)&a1, (void*)&a2, (void*)&a3,
                        (void*)&a4, (void*)&a5, (void*)&a6};
        (void)hipLaunchCooperativeKernel((const void*)k_gru, dim3(256), dim3(512),
                                         args, 0, stream);
    }

    k_out<<<dim3(400), 256, 0, stream>>>(hfrag, WoT, bo, out);
}

// Round 2
// 932.850 us; speedup vs baseline: 1.5181x; 1.5181x over previous
//
#include <hip/hip_runtime.h>

#define BS   256
#define HID  1024
#define KIN  8000
#define TST  100
#define ACTD 32
#define OUTD 64
#define KTOT 1056            // 1024 (Wh) + 32 (Wi) concatenated K
#define WP   1104            // Wlds row pitch in halfs (552 dw, %32==8 -> uniform banks)
#define HEXCH (16 * 32 * 512)  // one h buffer: 16 rgrp x 32 kb x 512 u16 (512 KB)

typedef __attribute__((ext_vector_type(8))) _Float16 f16x8;
typedef __attribute__((ext_vector_type(4))) float f32x4;
typedef unsigned short u16;
typedef unsigned int   u32;
typedef unsigned long long u64;

__device__ __forceinline__ u16 f2h(float f) {
    union { _Float16 h; u16 u; } c;
    c.h = (_Float16)f;             // v_cvt_f16_f32, RNE
    return c.u;
}
// fast sigmoid/tanh: v_exp + v_rcp (no fp32 div sequence, no libm tanhf).
// tanh via -2|x| so exp underflows (never overflows) -> no NaN path.
__device__ __forceinline__ float sigm(float x) {
    return __builtin_amdgcn_rcpf(1.0f + __expf(-x));
}
__device__ __forceinline__ float tanh_fast(float x) {
    float e = __expf(-2.0f * fabsf(x));
    float t = (1.0f - e) * __builtin_amdgcn_rcpf(1.0f + e);
    return copysignf(t, x);
}

#define MFMA16(a, b, c) __builtin_amdgcn_mfma_f32_16x16x32_f16(a, b, c, 0, 0, 0)

// Memory-side coherent 16B load (two relaxed agent-scope u64 atomics).
__device__ __forceinline__ f16x8 aload(const u16* p) {
    union { u64 d[2]; f16x8 v; } u;
    const u64* q = (const u64*)(const void*)p;
    u.d[0] = __hip_atomic_load(q + 0, __ATOMIC_RELAXED, __HIP_MEMORY_SCOPE_AGENT);
    u.d[1] = __hip_atomic_load(q + 1, __ATOMIC_RELAXED, __HIP_MEMORY_SCOPE_AGENT);
    return u.v;
}

// ---------------- P1: WfT[c][k] = fp16(Wh[k][c] | Wi[k-1024][c]) ----------------
__global__ __launch_bounds__(256) void k_prep_w(const float* __restrict__ Wh,
                                                const float* __restrict__ Wi,
                                                u16* __restrict__ Wf) {
    __shared__ float T[32][33];
    const int k0 = blockIdx.x * 32;      // 33 tiles cover k=0..1055
    const int c0 = blockIdx.y * 32;
    const int tid = threadIdx.x;
    {
        int k = tid >> 3, c4 = (tid & 7) * 4;
        int kk = k0 + k;
        const float* src = (kk < HID) ? (Wh + (size_t)kk * 3072 + c0 + c4)
                                      : (Wi + (size_t)(kk - HID) * 3072 + c0 + c4);
        float4 v = *(const float4*)src;
        T[k][c4 + 0] = v.x; T[k][c4 + 1] = v.y; T[k][c4 + 2] = v.z; T[k][c4 + 3] = v.w;
    }
    __syncthreads();
    {
        int c = tid >> 3, k4 = (tid & 7) * 4;
        size_t base = (size_t)(c0 + c) * KTOT + k0 + k4;
#pragma unroll
        for (int j = 0; j < 4; j++) Wf[base + j] = f2h(T[k4 + j][c]);
    }
}

// ---------------- P2: WoT[n][k] = fp16(Wo[k][n]) ----------------
__global__ __launch_bounds__(256) void k_prep_wo(const float* __restrict__ Wo,
                                                 u16* __restrict__ WoT) {
    int idx = blockIdx.x * 256 + threadIdx.x;   // 65536
    int n = idx & 63, k = idx >> 6;
    WoT[(size_t)n * HID + k] = f2h(Wo[(size_t)k * OUTD + n]);
}

// ---------------- P3: action fp32 -> fp16 (layout preserved) ----------------
__global__ __launch_bounds__(256) void k_prep_act(const float* __restrict__ act,
                                                  u16* __restrict__ acth) {
    int i = (blockIdx.x * 256 + threadIdx.x) * 4;
    float4 v = *(const float4*)(act + i);
    ushort4 h = make_ushort4(f2h(v.x), f2h(v.y), f2h(v.z), f2h(v.w));
    *(ushort4*)(acth + i) = h;
}

// ---------------- h0 partial GEMM (fp32, split-K) ----------------
#define H0_SPLIT 10
#define H0_KC    800
__global__ __launch_bounds__(256) void k_h0(const float* __restrict__ x,
                                            const float* __restrict__ Win,
                                            float* __restrict__ part) {
    __shared__ float As[32][33];   // [k][m]
    __shared__ float Bs[32][68];   // [k][n]
    const int n0 = blockIdx.x * 64, m0 = blockIdx.y * 32, s = blockIdx.z;
    const int tid = threadIdx.x;
    const int tm = tid >> 4, tn = tid & 15;
    float acc[2][4] = {};

    const int ar = tid >> 3, ac4 = (tid & 7) * 4;
    int br[2], bn4[2];
#pragma unroll
    for (int i = 0; i < 2; i++) { int e = tid + 256 * i; br[i] = e >> 4; bn4[i] = (e & 15) * 4; }
    const int k0 = s * H0_KC;

    float4 aReg = *(const float4*)(x + (size_t)(m0 + ar) * KIN + k0 + ac4);
    float4 bReg0 = *(const float4*)(Win + (size_t)(k0 + br[0]) * HID + n0 + bn4[0]);
    float4 bReg1 = *(const float4*)(Win + (size_t)(k0 + br[1]) * HID + n0 + bn4[1]);

    for (int it = 0; it < 25; it++) {
        __syncthreads();
        As[ac4 + 0][ar] = aReg.x; As[ac4 + 1][ar] = aReg.y;
        As[ac4 + 2][ar] = aReg.z; As[ac4 + 3][ar] = aReg.w;
        *(float4*)&Bs[br[0]][bn4[0]] = bReg0;
        *(float4*)&Bs[br[1]][bn4[1]] = bReg1;
        if (it < 24) {
            int kn = k0 + (it + 1) * 32;
            aReg  = *(const float4*)(x + (size_t)(m0 + ar) * KIN + kn + ac4);
            bReg0 = *(const float4*)(Win + (size_t)(kn + br[0]) * HID + n0 + bn4[0]);
            bReg1 = *(const float4*)(Win + (size_t)(kn + br[1]) * HID + n0 + bn4[1]);
        }
        __syncthreads();
#pragma unroll
        for (int kk = 0; kk < 32; kk++) {
            float a0 = As[kk][tm * 2], a1 = As[kk][tm * 2 + 1];
            float4 b = *(float4*)&Bs[kk][tn * 4];
            acc[0][0] = fmaf(a0, b.x, acc[0][0]); acc[0][1] = fmaf(a0, b.y, acc[0][1]);
            acc[0][2] = fmaf(a0, b.z, acc[0][2]); acc[0][3] = fmaf(a0, b.w, acc[0][3]);
            acc[1][0] = fmaf(a1, b.x, acc[1][0]); acc[1][1] = fmaf(a1, b.y, acc[1][1]);
            acc[1][2] = fmaf(a1, b.z, acc[1][2]); acc[1][3] = fmaf(a1, b.w, acc[1][3]);
        }
    }
    float* dst = part + (size_t)s * (BS * HID);
#pragma unroll
    for (int i = 0; i < 2; i++) {
        float4 v = make_float4(acc[i][0], acc[i][1], acc[i][2], acc[i][3]);
        *(float4*)(dst + (size_t)(m0 + tm * 2 + i) * HID + n0 + tn * 4) = v;
    }
}

// reduce partials; write fp32 h0 and fragment-order fp16 h0 into hfrag buf 0.
__global__ __launch_bounds__(256) void k_h0red(const float* __restrict__ part,
                                               const float* __restrict__ b_in,
                                               float* __restrict__ h0,
                                               u16* __restrict__ hfrag) {
    int idx = (blockIdx.x * 256 + threadIdx.x) * 4;
    float4 sv = *(const float4*)(part + idx);
#pragma unroll
    for (int p = 1; p < H0_SPLIT; p++) {
        float4 v = *(const float4*)(part + (size_t)p * (BS * HID) + idx);
        sv.x += v.x; sv.y += v.y; sv.z += v.z; sv.w += v.w;
    }
    int n = idx & (HID - 1);
    float4 b = *(const float4*)(b_in + n);
    sv.x = fmaxf(sv.x + b.x, 0.f); sv.y = fmaxf(sv.y + b.y, 0.f);
    sv.z = fmaxf(sv.z + b.z, 0.f); sv.w = fmaxf(sv.w + b.w, 0.f);
    *(float4*)(h0 + idx) = sv;
    int row = idx >> 10;
    float vv[4] = {sv.x, sv.y, sv.z, sv.w};
#pragma unroll
    for (int i = 0; i < 4; i++) {
        int c = n + i;
        int lane = ((c & 31) >> 3) * 16 + (row & 15);
        size_t off = ((size_t)(row >> 4) * 32 + (c >> 5)) * 512 + lane * 8 + (c & 7);
        __hip_atomic_store(hfrag + off, f2h(vv[i]), __ATOMIC_RELAXED, __HIP_MEMORY_SCOPE_AGENT);
    }
}

// ---------------- persistent GRU: all 100 steps in one cooperative launch ----------------
// 256 blocks x 512 thr. Block = 16 j-cols x 64 b-rows; bx: j0=(bx>>2)*16, bt=bx&3.
// Weights in LDS once. h exchange in fragment order (dense 1KB chunks).
// R11 = R9's proven barrier funnel (tid0-only poll -- R10's every-wave poll
// caused 512 wave-level pollers per counter and regressed 832->1213 us) plus
// the R10 keepers:
//  (a) hfrag = 101 per-step buffers; exchange store IS the output (no scattered
//      2B outs stores in the drain; WRITE_SIZE halved, verified R10);
//  (b) fast v_exp+v_rcp activations on the critical kq==0 wave;
//  (c) final step skips add/poll (kernel-end drain covers k_out visibility).
__global__ __launch_bounds__(512, 1) void k_gru(const float* __restrict__ h0f,
                                                const u16* __restrict__ acth,
                                                const u16* __restrict__ Wf,
                                                const float* __restrict__ bi,
                                                const float* __restrict__ bhn,
                                                u16* __restrict__ hfrag,
                                                u32* __restrict__ bars) {
    __shared__ u16 Wlds[3 * 16 * WP];          // 106 KB
    __shared__ float RED[2 * 3 * 2 * 64 * 17]; // 52.2 KB, pitch 17 = conflict-free
    __shared__ u16 HST[4 * 256];               // 2 KB h-store staging (rgidx x 256 u16)

    const int tid = threadIdx.x;
    const int bx = blockIdx.x;
    const int j0 = (bx >> 2) * 16;
    const int bt = bx & 3;
    const int b0 = bt * 64;
    const int w = tid >> 6;
    const int bsup = w >> 2, kq = w & 3;
    const int lane = tid & 63;
    const int m16 = lane & 15, quad = lane >> 4;

    // ---- stage weight slice to LDS (once) ----
    for (int p = 0; p < 13; p++) {
        int c = tid + p * 512;                 // 6336 chunks of 8 halfs
        if (c < 6336) {
            int row = c / 132, kc = (c % 132) * 8;
            int g = row >> 4, jj = row & 15;
            int4 v = *(const int4*)(const void*)(Wf + (size_t)(g * HID + j0 + jj) * KTOT + kc);
            *(int4*)(void*)&Wlds[row * WP + kc] = v;
        }
    }

    // home-wave persistent state
    const int j = j0 + m16;
    float bir = 0, biz = 0, bin_ = 0, bh_ = 0;
    float hreg[2][4] = {};
    if (kq == 0) {
        bir = bi[j]; biz = bi[HID + j]; bin_ = bi[2 * HID + j]; bh_ = bhn[j];
#pragma unroll
        for (int sub = 0; sub < 2; sub++)
#pragma unroll
            for (int rg = 0; rg < 4; rg++)
                hreg[sub][rg] = h0f[(size_t)(b0 + bsup * 32 + sub * 16 + quad * 4 + rg) * HID + j];
    }
    __syncthreads();

    const int kst = kq * 256 + (kq ? 32 : 0);  // {0,288,544,800}
    const int iters = kq ? 8 : 9;
    const int kb0 = kst >> 5;                  // {0,9,17,25}
    const int koff = quad * 8;
    const int rgb = b0 >> 4;                   // block's first rgrp
    const int rgrp0 = rgb + bsup * 2;          // this wave's A rgrp (sub0)
    const int row0 = b0 + bsup * 32 + m16;
    const u16* wbr = &Wlds[(0 * 16 + m16) * WP];
    const u16* wbz = &Wlds[(1 * 16 + m16) * WP];
    const u16* wbn = &Wlds[(2 * 16 + m16) * WP];
    const int jb = j0 >> 5;                    // k-chunk col index of this j-tile
    const int halfbase = (j0 & 16) ? 256 : 0;  // u16 offset of our 512B half-chunk
    u32* ctr = bars + bt * 32;                 // 128B-strided group counters

    // dense h-store map: threads 0..255 each write one u64 (4 u16) = full 2 KB HST
    const int srg = tid >> 6, sq = tid & 63;   // rgidx (0..3), u64-within-half (0..63)

    for (int t = 0; t < TST; t++) {
        const u16* pbase = hfrag + (size_t)t * HEXCH;
        u16* nbase = hfrag + (size_t)(t + 1) * HEXCH;
        const u16* actp0 = acth + (size_t)row0 * (TST * ACTD) + t * ACTD + koff;
        const u16* actp1 = actp0 + 16 * (TST * ACTD);

        // ---- PROLOGUE: issue ALL A-loads back-to-back (latency overlap) ----
        f16x8 a0s[9], a1s[9];
#pragma unroll
        for (int kt = 0; kt < 9; kt++) {
            if (kt < iters) {
                if (kq == 3 && kt == 7) {      // action block (read-only, cached)
                    a0s[kt] = *(const f16x8*)(const void*)actp0;
                    a1s[kt] = *(const f16x8*)(const void*)actp1;
                } else {                       // dense 1KB fragment chunks, uncached
                    const int kb = kb0 + kt;
                    a0s[kt] = aload(pbase + ((size_t)(rgrp0 * 32 + kb) << 9) + lane * 8);
                    a1s[kt] = aload(pbase + ((size_t)((rgrp0 + 1) * 32 + kb) << 9) + lane * 8);
                }
            }
        }

        f32x4 aR[2] = {{0,0,0,0},{0,0,0,0}}, aZ[2] = {{0,0,0,0},{0,0,0,0}};
        f32x4 aN[2] = {{0,0,0,0},{0,0,0,0}}, aI[2] = {{0,0,0,0},{0,0,0,0}};

#pragma unroll
        for (int kt = 0; kt < 9; kt++) {
            if (kt < iters) {
                const int k = kst + kt * 32;
                f16x8 a0 = a0s[kt], a1 = a1s[kt];
                f16x8 wr = *(const f16x8*)&wbr[k + koff];
                f16x8 wz = *(const f16x8*)&wbz[k + koff];
                f16x8 wn = *(const f16x8*)&wbn[k + koff];
                aR[0] = MFMA16(a0, wr, aR[0]);  aR[1] = MFMA16(a1, wr, aR[1]);
                aZ[0] = MFMA16(a0, wz, aZ[0]);  aZ[1] = MFMA16(a1, wz, aZ[1]);
                if (kq == 3 && kt == 7) {
                    aI[0] = MFMA16(a0, wn, aI[0]);  aI[1] = MFMA16(a1, wn, aI[1]);
                } else {
                    aN[0] = MFMA16(a0, wn, aN[0]);  aN[1] = MFMA16(a1, wn, aN[1]);
                }
            }
        }

        if (kq != 0) {
#pragma unroll
            for (int sub = 0; sub < 2; sub++) {
                float* d = &RED[(((bsup * 3 + (kq - 1)) * 2 + sub) * 64 + lane) * 17];
#pragma unroll
                for (int i = 0; i < 4; i++) {
                    d[i]      = aR[sub][i];
                    d[4 + i]  = aZ[sub][i];
                    d[8 + i]  = aN[sub][i];
                    d[12 + i] = aI[sub][i];
                }
            }
        }
        __syncthreads();                       // sync#1
        if (kq == 0) {
#pragma unroll
            for (int sub = 0; sub < 2; sub++) {
                float R[4], Z[4], N[4], I[4];
#pragma unroll
                for (int rg = 0; rg < 4; rg++) {
                    R[rg] = aR[sub][rg]; Z[rg] = aZ[sub][rg];
                    N[rg] = aN[sub][rg]; I[rg] = aI[sub][rg];
                }
#pragma unroll
                for (int src = 0; src < 3; src++) {
                    const float* d = &RED[(((bsup * 3 + src) * 2 + sub) * 64 + lane) * 17];
#pragma unroll
                    for (int rg = 0; rg < 4; rg++) {
                        R[rg] += d[rg]; Z[rg] += d[4 + rg];
                        N[rg] += d[8 + rg]; I[rg] += d[12 + rg];
                    }
                }
                const int rgidx = bsup * 2 + sub;
                const int lh = ((j & 15) >> 3) * 16 + quad * 4;   // lane-in-half base
#pragma unroll
                for (int rg = 0; rg < 4; rg++) {
                    float r = sigm(R[rg] + bir);
                    float z = sigm(Z[rg] + biz);
                    float n = tanh_fast(I[rg] + bin_ + r * (N[rg] + bh_));
                    float hnew = (1.0f - z) * n + z * hreg[sub][rg];
                    hreg[sub][rg] = hnew;
                    HST[rgidx * 256 + (lh + rg) * 8 + (j & 7)] = f2h(hnew);  // LDS scatter
                }
            }
        }
        __syncthreads();                       // sync#2 (HST ready, RED reads done)

        // ---- dense coalesced h-exchange store (threads 0..255, one u64 each) ----
        if (tid < 256) {
            u64 v = *(const u64*)(const void*)&HST[srg * 256 + sq * 4];
            u64* dst = (u64*)(void*)(nbase + (((size_t)(rgb + srg) * 32 + jb) << 9)
                                     + halfbase + sq * 4);
            __hip_atomic_store(dst, v, __ATOMIC_RELAXED, __HIP_MEMORY_SCOPE_AGENT);
        }

        // ---- per-bt group barrier (64 blocks): tid0-only add+poll (R9 funnel) ----
        if (t < TST - 1) {
            __builtin_amdgcn_s_waitcnt(0);     // stores acked at coherence point
            __syncthreads();                   // sync#3
            if (tid == 0) {
                __hip_atomic_fetch_add(ctr, 1u, __ATOMIC_RELAXED, __HIP_MEMORY_SCOPE_AGENT);
                u32 tgt = 64u * (u32)(t + 1);
                while (__hip_atomic_load(ctr, __ATOMIC_RELAXED, __HIP_MEMORY_SCOPE_AGENT) < tgt)
                    __builtin_amdgcn_s_sleep(1);
            }
            __syncthreads();                   // sync#4
        }
        // final step: stores drain at kernel end; next kernel acquires caches.
    }
}

// ---------------- k_out: out[b][t][:] = h_{t+1}[b] @ Wo + bo ----------------
// A comes straight from the fragment-order h buffers: chunk (t+1, rgrp, kb)
// holds the exact MFMA A-fragment (lane = kq*16 + row, 8 k-elems). No LDS.
__global__ __launch_bounds__(256) void k_out(const u16* __restrict__ hfrag,
                                             const u16* __restrict__ WoT,
                                             const float* __restrict__ bo,
                                             float* __restrict__ out) {
    const int tid = threadIdx.x;
    const int t = blockIdx.x % TST;            // 0..99
    const int rg4 = blockIdx.x / TST;          // 0..3
    const int w = tid >> 6, lane = tid & 63;
    const int m16 = lane & 15, quad = lane >> 4;
    const int rgrp = rg4 * 4 + w;              // 0..15 (16 batch rows each)

    const u16* abase = hfrag + (size_t)(t + 1) * HEXCH
                     + (((size_t)rgrp * 32) << 9) + lane * 8;
    const u16* bbase = WoT + (size_t)m16 * HID + quad * 8;
    f32x4 acc[4] = {{0,0,0,0},{0,0,0,0},{0,0,0,0},{0,0,0,0}};

#pragma unroll 4
    for (int kb = 0; kb < 32; kb++) {
        f16x8 a = *(const f16x8*)(const void*)(abase + (kb << 9));
        const u16* bp = bbase + kb * 32;
#pragma unroll
        for (int nt = 0; nt < 4; nt++) {
            f16x8 b = *(const f16x8*)(const void*)(bp + (size_t)nt * 16 * HID);
            acc[nt] = __builtin_amdgcn_mfma_f32_16x16x32_f16(a, b, acc[nt], 0, 0, 0);
        }
    }
    const int brow = rgrp * 16 + quad * 4;     // C layout: col=lane&15, row=quad*4+reg
#pragma unroll
    for (int nt = 0; nt < 4; nt++) {
        int n = nt * 16 + m16;
        float bov = bo[n];
#pragma unroll
        for (int rg = 0; rg < 4; rg++) {
            int b = brow + rg;
            out[((size_t)b * TST + t) * OUTD + n] = acc[nt][rg] + bov;
        }
    }
}

extern "C" void kernel_launch(void* const* d_in, const int* in_sizes, int n_in,
                              void* d_out, int out_size, void* d_ws, size_t ws_size,
                              hipStream_t stream) {
    const float* history = (const float*)d_in[0];
    const float* action  = (const float*)d_in[1];
    const float* W_in    = (const float*)d_in[2];
    const float* b_in    = (const float*)d_in[3];
    const float* Wi      = (const float*)d_in[4];
    const float* bi      = (const float*)d_in[5];
    const float* Wh      = (const float*)d_in[6];
    const float* bhn     = (const float*)d_in[7];
    const float* Wo      = (const float*)d_in[8];
    const float* bo      = (const float*)d_in[9];
    float* out = (float*)d_out;

    char* ws = (char*)d_ws;
    float* hbuf0 = (float*)(ws + 0);                    // 1 MB (fp32 h0)
    u16*   Wf    = (u16*)  (ws + (3u << 20));           // 6.33 MB
    u16*   WoT   = (u16*)  (ws + (10u << 20));          // 128 KB
    u16*   acth  = (u16*)  (ws + (11u << 20));          // 1.6 MB
    float* part  = (float*)(ws + (13u << 20));          // 10 MB (13..23 MiB)
    u32*   bars  = (u32*)  (ws + (23u << 20));          // 512 B group counters
    u16*   hfrag = (u16*)  (ws + (24u << 20));          // 101 x 512 KB = 50.5 MB

    (void)hipMemsetAsync(bars, 0, 512, stream);
    k_prep_w<<<dim3(33, 96), 256, 0, stream>>>(Wh, Wi, Wf);
    k_prep_wo<<<256, 256, 0, stream>>>(Wo, WoT);
    k_prep_act<<<800, 256, 0, stream>>>(action, acth);
    k_h0<<<dim3(16, 8, H0_SPLIT), 256, 0, stream>>>(history, W_in, part);
    k_h0red<<<256, 256, 0, stream>>>(part, b_in, hbuf0, hfrag);

    {
        const float* a0 = hbuf0; const u16* a1 = acth; const u16* a2 = Wf;
        const float* a3 = bi;    const float* a4 = bhn;
        u16* a5 = hfrag;         u32* a6 = bars;
        void* args[] = {(void*)&a0, (void*)&a1, (void*)&a2, (void*)&a3,
                        (void*)&a4, (void*)&a5, (void*)&a6};
        (void)hipLaunchCooperativeKernel((const void*)k_gru, dim3(256), dim3(512),
                                         args, 0, stream);
    }

    k_out<<<dim3(400), 256, 0, stream>>>(hfrag, WoT, bo, out);
}

// Round 4
// 922.878 us; speedup vs baseline: 1.5345x; 1.0108x over previous
//
#include <hip/hip_runtime.h>

#define BS   256
#define HID  1024
#define KIN  8000
#define TST  100
#define ACTD 32
#define OUTD 64
#define KTOT 1056            // 1024 (Wh) + 32 (Wi) concatenated K
#define WP   1104            // Wlds row pitch in halfs (552 dw, %32==8 -> uniform banks)
#define HEXCH (16 * 32 * 512)  // one h buffer: 16 rgrp x 32 kb x 512 u16 (512 KB)
#define POLL_CAP (1u << 18)    // bounded spin: protocol bug -> wrong result, NOT a hang

typedef __attribute__((ext_vector_type(8))) _Float16 f16x8;
typedef __attribute__((ext_vector_type(4))) float f32x4;
typedef unsigned short u16;
typedef unsigned int   u32;
typedef unsigned long long u64;

__device__ __forceinline__ u16 f2h(float f) {
    union { _Float16 h; u16 u; } c;
    c.h = (_Float16)f;             // v_cvt_f16_f32, RNE
    return c.u;
}
// fast sigmoid/tanh: v_exp + v_rcp. tanh via -2|x| (exp underflows, never NaN).
__device__ __forceinline__ float sigm(float x) {
    return __builtin_amdgcn_rcpf(1.0f + __expf(-x));
}
__device__ __forceinline__ float tanh_fast(float x) {
    float e = __expf(-2.0f * fabsf(x));
    float t = (1.0f - e) * __builtin_amdgcn_rcpf(1.0f + e);
    return copysignf(t, x);
}

#define MFMA16(a, b, c) __builtin_amdgcn_mfma_f32_16x16x32_f16(a, b, c, 0, 0, 0)

// Memory-side coherent 16B load (two relaxed agent-scope u64 atomics).
__device__ __forceinline__ f16x8 aload(const u16* p) {
    union { u64 d[2]; f16x8 v; } u;
    const u64* q = (const u64*)(const void*)p;
    u.d[0] = __hip_atomic_load(q + 0, __ATOMIC_RELAXED, __HIP_MEMORY_SCOPE_AGENT);
    u.d[1] = __hip_atomic_load(q + 1, __ATOMIC_RELAXED, __HIP_MEMORY_SCOPE_AGENT);
    return u.v;
}

__device__ __forceinline__ void pollctr(u32* ctr, u32 tgt) {
    for (u32 it = 0; it < POLL_CAP; ++it) {
        if (__hip_atomic_load(ctr, __ATOMIC_RELAXED, __HIP_MEMORY_SCOPE_AGENT) >= tgt)
            return;
        __builtin_amdgcn_s_sleep(1);
    }
}

// ---------------- P1: WfT[c][k] = fp16(Wh[k][c] | Wi[k-1024][c]) ----------------
__global__ __launch_bounds__(256) void k_prep_w(const float* __restrict__ Wh,
                                                const float* __restrict__ Wi,
                                                u16* __restrict__ Wf) {
    __shared__ float T[32][33];
    const int k0 = blockIdx.x * 32;      // 33 tiles cover k=0..1055
    const int c0 = blockIdx.y * 32;
    const int tid = threadIdx.x;
    {
        int k = tid >> 3, c4 = (tid & 7) * 4;
        int kk = k0 + k;
        const float* src = (kk < HID) ? (Wh + (size_t)kk * 3072 + c0 + c4)
                                      : (Wi + (size_t)(kk - HID) * 3072 + c0 + c4);
        float4 v = *(const float4*)src;
        T[k][c4 + 0] = v.x; T[k][c4 + 1] = v.y; T[k][c4 + 2] = v.z; T[k][c4 + 3] = v.w;
    }
    __syncthreads();
    {
        int c = tid >> 3, k4 = (tid & 7) * 4;
        size_t base = (size_t)(c0 + c) * KTOT + k0 + k4;
#pragma unroll
        for (int j = 0; j < 4; j++) Wf[base + j] = f2h(T[k4 + j][c]);
    }
}

// ---------------- P2: WoT[n][k] = fp16(Wo[k][n]) ----------------
__global__ __launch_bounds__(256) void k_prep_wo(const float* __restrict__ Wo,
                                                 u16* __restrict__ WoT) {
    int idx = blockIdx.x * 256 + threadIdx.x;   // 65536
    int n = idx & 63, k = idx >> 6;
    WoT[(size_t)n * HID + k] = f2h(Wo[(size_t)k * OUTD + n]);
}

// ---------------- P3: action fp32 -> fp16 (layout preserved) ----------------
__global__ __launch_bounds__(256) void k_prep_act(const float* __restrict__ act,
                                                  u16* __restrict__ acth) {
    int i = (blockIdx.x * 256 + threadIdx.x) * 4;
    float4 v = *(const float4*)(act + i);
    ushort4 h = make_ushort4(f2h(v.x), f2h(v.y), f2h(v.z), f2h(v.w));
    *(ushort4*)(acth + i) = h;
}

// ---------------- h0 partial GEMM (fp32, split-K) ----------------
#define H0_SPLIT 10
#define H0_KC    800
__global__ __launch_bounds__(256) void k_h0(const float* __restrict__ x,
                                            const float* __restrict__ Win,
                                            float* __restrict__ part) {
    __shared__ float As[32][33];   // [k][m]
    __shared__ float Bs[32][68];   // [k][n]
    const int n0 = blockIdx.x * 64, m0 = blockIdx.y * 32, s = blockIdx.z;
    const int tid = threadIdx.x;
    const int tm = tid >> 4, tn = tid & 15;
    float acc[2][4] = {};

    const int ar = tid >> 3, ac4 = (tid & 7) * 4;
    int br[2], bn4[2];
#pragma unroll
    for (int i = 0; i < 2; i++) { int e = tid + 256 * i; br[i] = e >> 4; bn4[i] = (e & 15) * 4; }
    const int k0 = s * H0_KC;

    float4 aReg = *(const float4*)(x + (size_t)(m0 + ar) * KIN + k0 + ac4);
    float4 bReg0 = *(const float4*)(Win + (size_t)(k0 + br[0]) * HID + n0 + bn4[0]);
    float4 bReg1 = *(const float4*)(Win + (size_t)(k0 + br[1]) * HID + n0 + bn4[1]);

    for (int it = 0; it < 25; it++) {
        __syncthreads();
        As[ac4 + 0][ar] = aReg.x; As[ac4 + 1][ar] = aReg.y;
        As[ac4 + 2][ar] = aReg.z; As[ac4 + 3][ar] = aReg.w;
        *(float4*)&Bs[br[0]][bn4[0]] = bReg0;
        *(float4*)&Bs[br[1]][bn4[1]] = bReg1;
        if (it < 24) {
            int kn = k0 + (it + 1) * 32;
            aReg  = *(const float4*)(x + (size_t)(m0 + ar) * KIN + kn + ac4);
            bReg0 = *(const float4*)(Win + (size_t)(kn + br[0]) * HID + n0 + bn4[0]);
            bReg1 = *(const float4*)(Win + (size_t)(kn + br[1]) * HID + n0 + bn4[1]);
        }
        __syncthreads();
#pragma unroll
        for (int kk = 0; kk < 32; kk++) {
            float a0 = As[kk][tm * 2], a1 = As[kk][tm * 2 + 1];
            float4 b = *(float4*)&Bs[kk][tn * 4];
            acc[0][0] = fmaf(a0, b.x, acc[0][0]); acc[0][1] = fmaf(a0, b.y, acc[0][1]);
            acc[0][2] = fmaf(a0, b.z, acc[0][2]); acc[0][3] = fmaf(a0, b.w, acc[0][3]);
            acc[1][0] = fmaf(a1, b.x, acc[1][0]); acc[1][1] = fmaf(a1, b.y, acc[1][1]);
            acc[1][2] = fmaf(a1, b.z, acc[1][2]); acc[1][3] = fmaf(a1, b.w, acc[1][3]);
        }
    }
    float* dst = part + (size_t)s * (BS * HID);
#pragma unroll
    for (int i = 0; i < 2; i++) {
        float4 v = make_float4(acc[i][0], acc[i][1], acc[i][2], acc[i][3]);
        *(float4*)(dst + (size_t)(m0 + tm * 2 + i) * HID + n0 + tn * 4) = v;
    }
}

// reduce partials; write fp32 h0 and fragment-order fp16 h0 into hfrag buf 0.
__global__ __launch_bounds__(256) void k_h0red(const float* __restrict__ part,
                                               const float* __restrict__ b_in,
                                               float* __restrict__ h0,
                                               u16* __restrict__ hfrag) {
    int idx = (blockIdx.x * 256 + threadIdx.x) * 4;
    float4 sv = *(const float4*)(part + idx);
#pragma unroll
    for (int p = 1; p < H0_SPLIT; p++) {
        float4 v = *(const float4*)(part + (size_t)p * (BS * HID) + idx);
        sv.x += v.x; sv.y += v.y; sv.z += v.z; sv.w += v.w;
    }
    int n = idx & (HID - 1);
    float4 b = *(const float4*)(b_in + n);
    sv.x = fmaxf(sv.x + b.x, 0.f); sv.y = fmaxf(sv.y + b.y, 0.f);
    sv.z = fmaxf(sv.z + b.z, 0.f); sv.w = fmaxf(sv.w + b.w, 0.f);
    *(float4*)(h0 + idx) = sv;
    int row = idx >> 10;
    float vv[4] = {sv.x, sv.y, sv.z, sv.w};
#pragma unroll
    for (int i = 0; i < 4; i++) {
        int c = n + i;
        int lane = ((c & 31) >> 3) * 16 + (row & 15);
        size_t off = ((size_t)(row >> 4) * 32 + (c >> 5)) * 512 + lane * 8 + (c & 7);
        __hip_atomic_store(hfrag + off, f2h(vv[i]), __ATOMIC_RELAXED, __HIP_MEMORY_SCOPE_AGENT);
    }
}

// ---- helper pieces for k_gru (plain inline functions, no ragged unrolls) ----
__device__ __forceinline__ void issue8(f16x8* dst, const u16* base, int rgrp,
                                       int kb0, int lane) {
#pragma unroll
    for (int kt = 0; kt < 8; kt++)
        dst[kt] = aload(base + ((size_t)(rgrp * 32 + kb0 + kt) << 9) + lane * 8);
}

__device__ __forceinline__ void mfma_stage(const f16x8* src, const u16* wbr,
                                           const u16* wbz, const u16* wbn,
                                           int kst, int koff, int kq,
                                           f32x4& vR, f32x4& vZ, f32x4& vN, f32x4& vI) {
#pragma unroll
    for (int kt = 0; kt < 8; kt++) {
        const int k = kst + kt * 32;
        f16x8 a = src[kt];
        f16x8 wr = *(const f16x8*)&wbr[k + koff];
        f16x8 wz = *(const f16x8*)&wbz[k + koff];
        f16x8 wn = *(const f16x8*)&wbn[k + koff];
        vR = MFMA16(a, wr, vR);
        vZ = MFMA16(a, wz, vZ);
        vN = MFMA16(a, wn, vN);
    }
    if (kq == 3) {                         // action block, k=1024..1055 (Wi rows)
        f16x8 a = src[8];
        f16x8 wr = *(const f16x8*)&wbr[1024 + koff];
        f16x8 wz = *(const f16x8*)&wbz[1024 + koff];
        f16x8 wn = *(const f16x8*)&wbn[1024 + koff];
        vR = MFMA16(a, wr, vR);
        vZ = MFMA16(a, wz, vZ);
        vI = MFMA16(a, wn, vI);            // i_n kept separate from h_n
    }
}

__device__ __forceinline__ void red_write(float* REDp, int bsup, int kq, int lane,
                                          const f32x4& vR, const f32x4& vZ,
                                          const f32x4& vN, const f32x4& vI) {
    float* d = &REDp[((bsup * 3 + (kq - 1)) * 64 + lane) * 17];
#pragma unroll
    for (int i = 0; i < 4; i++) {
        d[i] = vR[i]; d[4 + i] = vZ[i]; d[8 + i] = vN[i]; d[12 + i] = vI[i];
    }
}

__device__ __forceinline__ void finish_stage(const float* REDp, const f32x4& vR,
                                             const f32x4& vZ, const f32x4& vN,
                                             const f32x4& vI, float bir, float biz,
                                             float bin_, float bh_, float* hreg,
                                             u16* HSTx, int bsup, int lane,
                                             int lh, int j7) {
    float R[4], Z[4], N[4], I[4];
#pragma unroll
    for (int rg = 0; rg < 4; rg++) {
        R[rg] = vR[rg]; Z[rg] = vZ[rg]; N[rg] = vN[rg]; I[rg] = vI[rg];
    }
#pragma unroll
    for (int src = 0; src < 3; src++) {
        const float* d = &REDp[((bsup * 3 + src) * 64 + lane) * 17];
#pragma unroll
        for (int rg = 0; rg < 4; rg++) {
            R[rg] += d[rg]; Z[rg] += d[4 + rg];
            N[rg] += d[8 + rg]; I[rg] += d[12 + rg];
        }
    }
#pragma unroll
    for (int rg = 0; rg < 4; rg++) {
        float r = sigm(R[rg] + bir);
        float z = sigm(Z[rg] + biz);
        float n = tanh_fast(I[rg] + bin_ + r * (N[rg] + bh_));
        float hnew = (1.0f - z) * n + z * hreg[rg];
        hreg[rg] = hnew;
        HSTx[bsup * 256 + (lh + rg) * 8 + j7] = f2h(hnew);
    }
}

__device__ __forceinline__ void store_stage(const u16* HSTx, int rgbase, u16* nb,
                                            int jb, int halfbase, int srg, int sq) {
    u64 v = *(const u64*)(const void*)&HSTx[srg * 256 + sq * 4];
    u64* dst = (u64*)(void*)(nb + ((size_t)((rgbase + srg) * 32 + jb) << 9)
                             + halfbase + sq * 4);
    __hip_atomic_store(dst, v, __ATOMIC_RELAXED, __HIP_MEMORY_SCOPE_AGENT);
}

// ---------------- persistent GRU: two interleaved half-chains (A/B pipeline) ----------------
// 256 blocks x 512 thr. Block bx: j0=(bx>>2)*16, pair p=bx&3.
// Chain A = rows p*32..+31 (rgrps 2p,2p+1, group p); chain B = rows 128+p*32..
// (rgrps 8+2p,8+2p+1, group 4+p). 8 groups x 64 blocks; counters 128B-strided;
// tid0-only poll (R10 lesson: distributed polling on one line is catastrophic);
// bounded spins (R12 lesson: never ship an unvalidated unbounded spin).
// Weights in LDS (R11-proven); per stage each wave does 8 reg-staged aloads +
// 24-27 MFMAs. One chain's store-drain/signal/poll/aload RTT hides under the
// other chain's MFMA+finish compute.
__global__ __launch_bounds__(512, 1) void k_gru(const float* __restrict__ h0f,
                                                const u16* __restrict__ acth,
                                                const u16* __restrict__ Wf,
                                                const float* __restrict__ bi,
                                                const float* __restrict__ bhn,
                                                u16* __restrict__ hfrag,
                                                u32* __restrict__ bars) {
    __shared__ u16 Wlds[3 * 16 * WP];      // 106 KB
    __shared__ float RED[2 * 3 * 64 * 17]; // 26.1 KB, pitch 17 conflict-free
    __shared__ u16 HSTA[512], HSTB[512];   // 1 KB per stage (2 rgrp x 256 u16)

    const int tid = threadIdx.x;
    const int bx = blockIdx.x;
    const int j0 = (bx >> 2) * 16;
    const int p  = bx & 3;
    const int w = tid >> 6;
    const int bsup = w >> 2, kq = w & 3;
    const int lane = tid & 63;
    const int m16 = lane & 15, quad = lane >> 4;

    const int kst = kq * 256;
    const int kb0 = kq * 8;
    const int koff = quad * 8;
    const int rgA = p * 2 + bsup;
    const int rgB = 8 + p * 2 + bsup;
    const int rowA = p * 32 + bsup * 16 + m16;
    const int rowB = 128 + rowA;
    const int jb = j0 >> 5;
    const int halfbase = (j0 & 16) ? 256 : 0;
    u32* ctrA = bars + p * 32;
    u32* ctrB = bars + (4 + p) * 32;
    const int srg = tid >> 6, sq = tid & 63;   // store map (tid<128)
    const int j = j0 + m16;
    const int lh = ((j & 15) >> 3) * 16 + quad * 4;
    const int j7 = j & 7;

    // ---- pre-issue chain-A loads for t=0 (buf 0 from k_h0red; no LDS dep) ----
    f16x8 aA[9];
    issue8(aA, hfrag, rgA, kb0, lane);
    if (kq == 3)
        aA[8] = *(const f16x8*)(const void*)(acth + (size_t)rowA * (TST * ACTD) + koff);

    // ---- stage weight slice to LDS (once; overlaps the aloads above) ----
    for (int pp = 0; pp < 13; pp++) {
        int c = tid + pp * 512;                // 6336 chunks of 8 halfs
        if (c < 6336) {
            int row = c / 132, kc = (c % 132) * 8;
            int g = row >> 4, jj = row & 15;
            int4 v = *(const int4*)(const void*)(Wf + (size_t)(g * HID + j0 + jj) * KTOT + kc);
            *(int4*)(void*)&Wlds[row * WP + kc] = v;
        }
    }

    // ---- per-chain persistent state (finisher waves kq==0) ----
    float bir = 0, biz = 0, bin_ = 0, bh_ = 0;
    float hregA[4] = {}, hregB[4] = {};
    if (kq == 0) {
        bir = bi[j]; biz = bi[HID + j]; bin_ = bi[2 * HID + j]; bh_ = bhn[j];
#pragma unroll
        for (int rg = 0; rg < 4; rg++) {
            hregA[rg] = h0f[(size_t)(p * 32 + bsup * 16 + quad * 4 + rg) * HID + j];
            hregB[rg] = h0f[(size_t)(128 + p * 32 + bsup * 16 + quad * 4 + rg) * HID + j];
        }
    }
    __syncthreads();                           // Wlds ready

    const u16* wbr = &Wlds[(0 * 16 + m16) * WP];
    const u16* wbz = &Wlds[(1 * 16 + m16) * WP];
    const u16* wbn = &Wlds[(2 * 16 + m16) * WP];

    for (int t = 0; t < TST; t++) {
        const u16* bufT = hfrag + (size_t)t * HEXCH;
        u16* bufT1 = hfrag + (size_t)(t + 1) * HEXCH;

        // ---- A: MFMA (aA issued one phase earlier) ----
        f32x4 aRv = {0,0,0,0}, aZv = {0,0,0,0}, aNv = {0,0,0,0}, aIv = {0,0,0,0};
        mfma_stage(aA, wbr, wbz, wbn, kst, koff, kq, aRv, aZv, aNv, aIv);
        if (kq != 0) red_write(RED, bsup, kq, lane, aRv, aZv, aNv, aIv);

        // ---- poll B(t) ready (stored at end of iter t-1); doubles as A-RED barrier ----
        if (tid == 0 && t > 0) pollctr(ctrB, 128u * (u32)t);
        __syncthreads();                       // S1

        // ---- issue B loads early (latency hides under A-finish) ----
        f16x8 aB[9];
        issue8(aB, bufT, rgB, kb0, lane);
        if (kq == 3)
            aB[8] = *(const f16x8*)(const void*)(acth + (size_t)rowB * (TST * ACTD)
                                                 + t * ACTD + koff);

        if (kq == 0)
            finish_stage(RED, aRv, aZv, aNv, aIv, bir, biz, bin_, bh_,
                         hregA, HSTA, bsup, lane, lh, j7);
        __syncthreads();                       // S2 (HSTA ready, RED reads done)

        // ---- A-store h_A(t+1) + signal (waves 0-1; drain overlaps B compute) ----
        if (tid < 128) {
            store_stage(HSTA, p * 2, bufT1, jb, halfbase, srg, sq);
            __builtin_amdgcn_s_waitcnt(0);     // our 2 u64 stores acked
            if ((tid & 63) == 0 && t < TST - 1)
                __hip_atomic_fetch_add(ctrA, 1u, __ATOMIC_RELAXED, __HIP_MEMORY_SCOPE_AGENT);
        }

        // ---- B: MFMA ----
        f32x4 bRv = {0,0,0,0}, bZv = {0,0,0,0}, bNv = {0,0,0,0}, bIv = {0,0,0,0};
        mfma_stage(aB, wbr, wbz, wbn, kst, koff, kq, bRv, bZv, bNv, bIv);
        if (kq != 0) red_write(RED, bsup, kq, lane, bRv, bZv, bNv, bIv);

        // ---- poll A(t+1) ready (signaled above by all 64 blocks) ----
        if (tid == 0 && t < TST - 1) pollctr(ctrA, 128u * (u32)(t + 1));
        __syncthreads();                       // S3

        // ---- issue A(t+1) loads (waves 2-7 now; waves 0-1 after their B-store) ----
        if (t < TST - 1 && w >= 2) {
            issue8(aA, bufT1, rgA, kb0, lane);
            if (kq == 3)
                aA[8] = *(const f16x8*)(const void*)(acth + (size_t)rowA * (TST * ACTD)
                                                     + (t + 1) * ACTD + koff);
        }

        if (kq == 0)
            finish_stage(RED, bRv, bZv, bNv, bIv, bir, biz, bin_, bh_,
                         hregB, HSTB, bsup, lane, lh, j7);
        __syncthreads();                       // S4

        // ---- B-store h_B(t+1) + signal ----
        if (tid < 128) {
            store_stage(HSTB, 8 + p * 2, bufT1, jb, halfbase, srg, sq);
            __builtin_amdgcn_s_waitcnt(0);
            if ((tid & 63) == 0 && t < TST - 1)
                __hip_atomic_fetch_add(ctrB, 1u, __ATOMIC_RELAXED, __HIP_MEMORY_SCOPE_AGENT);
        }
        if (t < TST - 1 && w < 2)              // w<2 has kq in {0,1}: no action load
            issue8(aA, bufT1, rgA, kb0, lane);
        // last step: stores drain at kernel end; k_out acquires at launch.
    }
}

// ---------------- k_out: out[b][t][:] = h_{t+1}[b] @ Wo + bo ----------------
// A comes straight from the fragment-order h buffers: chunk (t+1, rgrp, kb)
// holds the exact MFMA A-fragment (lane = kq*16 + row, 8 k-elems). No LDS.
__global__ __launch_bounds__(256) void k_out(const u16* __restrict__ hfrag,
                                             const u16* __restrict__ WoT,
                                             const float* __restrict__ bo,
                                             float* __restrict__ out) {
    const int tid = threadIdx.x;
    const int t = blockIdx.x % TST;            // 0..99
    const int rg4 = blockIdx.x / TST;          // 0..3
    const int w = tid >> 6, lane = tid & 63;
    const int m16 = lane & 15, quad = lane >> 4;
    const int rgrp = rg4 * 4 + w;              // 0..15 (16 batch rows each)

    const u16* abase = hfrag + (size_t)(t + 1) * HEXCH
                     + (((size_t)rgrp * 32) << 9) + lane * 8;
    const u16* bbase = WoT + (size_t)m16 * HID + quad * 8;
    f32x4 acc[4] = {{0,0,0,0},{0,0,0,0},{0,0,0,0},{0,0,0,0}};

#pragma unroll 4
    for (int kb = 0; kb < 32; kb++) {
        f16x8 a = *(const f16x8*)(const void*)(abase + (kb << 9));
        const u16* bp = bbase + kb * 32;
#pragma unroll
        for (int nt = 0; nt < 4; nt++) {
            f16x8 b = *(const f16x8*)(const void*)(bp + (size_t)nt * 16 * HID);
            acc[nt] = __builtin_amdgcn_mfma_f32_16x16x32_f16(a, b, acc[nt], 0, 0, 0);
        }
    }
    const int brow = rgrp * 16 + quad * 4;     // C layout: col=lane&15, row=quad*4+reg
#pragma unroll
    for (int nt = 0; nt < 4; nt++) {
        int n = nt * 16 + m16;
        float bov = bo[n];
#pragma unroll
        for (int rg = 0; rg < 4; rg++) {
            int b = brow + rg;
            out[((size_t)b * TST + t) * OUTD + n] = acc[nt][rg] + bov;
        }
    }
}

extern "C" void kernel_launch(void* const* d_in, const int* in_sizes, int n_in,
                              void* d_out, int out_size, void* d_ws, size_t ws_size,
                              hipStream_t stream) {
    const float* history = (const float*)d_in[0];
    const float* action  = (const float*)d_in[1];
    const float* W_in    = (const float*)d_in[2];
    const float* b_in    = (const float*)d_in[3];
    const float* Wi      = (const float*)d_in[4];
    const float* bi      = (const float*)d_in[5];
    const float* Wh      = (const float*)d_in[6];
    const float* bhn     = (const float*)d_in[7];
    const float* Wo      = (const float*)d_in[8];
    const float* bo      = (const float*)d_in[9];
    float* out = (float*)d_out;

    char* ws = (char*)d_ws;
    float* hbuf0 = (float*)(ws + 0);                    // 1 MB (fp32 h0)
    u16*   Wf    = (u16*)  (ws + (3u << 20));           // 6.33 MB
    u16*   WoT   = (u16*)  (ws + (10u << 20));          // 128 KB
    u16*   acth  = (u16*)  (ws + (11u << 20));          // 1.6 MB
    float* part  = (float*)(ws + (13u << 20));          // 10 MB (13..23 MiB)
    u32*   bars  = (u32*)  (ws + (23u << 20));          // 1 KB: 8 group counters
    u16*   hfrag = (u16*)  (ws + (24u << 20));          // 101 x 512 KB = 50.5 MB

    (void)hipMemsetAsync(bars, 0, 1024, stream);
    k_prep_w<<<dim3(33, 96), 256, 0, stream>>>(Wh, Wi, Wf);
    k_prep_wo<<<256, 256, 0, stream>>>(Wo, WoT);
    k_prep_act<<<800, 256, 0, stream>>>(action, acth);
    k_h0<<<dim3(16, 8, H0_SPLIT), 256, 0, stream>>>(history, W_in, part);
    k_h0red<<<256, 256, 0, stream>>>(part, b_in, hbuf0, hfrag);

    {
        const float* a0 = hbuf0; const u16* a1 = acth; const u16* a2 = Wf;
        const float* a3 = bi;    const float* a4 = bhn;
        u16* a5 = hfrag;         u32* a6 = bars;
        void* args[] = {(void*)&a0, (void*)&a1, (void*)&a2, (void*)&a3,
                        (void*)&a4, (void*)&a5, (void*)&a6};
        (void)hipLaunchCooperativeKernel((const void*)k_gru, dim3(256), dim3(512),
                                         args, 0, stream);
    }

    k_out<<<dim3(400), 256, 0, stream>>>(hfrag, WoT, bo, out);
}

// Round 5
// 727.862 us; speedup vs baseline: 1.9457x; 1.2679x over previous
//
#include <hip/hip_runtime.h>

#define BS   256
#define HID  1024
#define KIN  8000
#define TST  100
#define ACTD 32
#define OUTD 64
#define KTOT 1056            // 1024 (Wh) + 32 (Wi) concatenated K
#define WP   1104            // Wlds row pitch in halfs (552 dw, %32==8 -> uniform banks)
#define HEXCH (16 * 32 * 512)  // one h buffer: 16 rgrp x 32 kb x 512 u16 (512 KB)
#define POLL_CAP (1u << 18)    // bounded spin: protocol bug -> wrong result, NOT a hang

typedef __attribute__((ext_vector_type(8))) _Float16 f16x8;
typedef __attribute__((ext_vector_type(4))) float f32x4;
typedef unsigned short u16;
typedef unsigned int   u32;
typedef unsigned long long u64;

__device__ __forceinline__ u16 f2h(float f) {
    union { _Float16 h; u16 u; } c;
    c.h = (_Float16)f;             // v_cvt_f16_f32, RNE
    return c.u;
}
// fast sigmoid/tanh: v_exp + v_rcp. tanh via -2|x| (exp underflows, never NaN).
__device__ __forceinline__ float sigm(float x) {
    return __builtin_amdgcn_rcpf(1.0f + __expf(-x));
}
__device__ __forceinline__ float tanh_fast(float x) {
    float e = __expf(-2.0f * fabsf(x));
    float t = (1.0f - e) * __builtin_amdgcn_rcpf(1.0f + e);
    return copysignf(t, x);
}

#define MFMA16(a, b, c) __builtin_amdgcn_mfma_f32_16x16x32_f16(a, b, c, 0, 0, 0)

// ---------------- P1: WfT[c][k] = fp16(Wh[k][c] | Wi[k-1024][c]) ----------------
__global__ __launch_bounds__(256) void k_prep_w(const float* __restrict__ Wh,
                                                const float* __restrict__ Wi,
                                                u16* __restrict__ Wf) {
    __shared__ float T[32][33];
    const int k0 = blockIdx.x * 32;      // 33 tiles cover k=0..1055
    const int c0 = blockIdx.y * 32;
    const int tid = threadIdx.x;
    {
        int k = tid >> 3, c4 = (tid & 7) * 4;
        int kk = k0 + k;
        const float* src = (kk < HID) ? (Wh + (size_t)kk * 3072 + c0 + c4)
                                      : (Wi + (size_t)(kk - HID) * 3072 + c0 + c4);
        float4 v = *(const float4*)src;
        T[k][c4 + 0] = v.x; T[k][c4 + 1] = v.y; T[k][c4 + 2] = v.z; T[k][c4 + 3] = v.w;
    }
    __syncthreads();
    {
        int c = tid >> 3, k4 = (tid & 7) * 4;
        size_t base = (size_t)(c0 + c) * KTOT + k0 + k4;
#pragma unroll
        for (int j = 0; j < 4; j++) Wf[base + j] = f2h(T[k4 + j][c]);
    }
}

// ---------------- P2: WoT[n][k] = fp16(Wo[k][n]) ----------------
__global__ __launch_bounds__(256) void k_prep_wo(const float* __restrict__ Wo,
                                                 u16* __restrict__ WoT) {
    int idx = blockIdx.x * 256 + threadIdx.x;   // 65536
    int n = idx & 63, k = idx >> 6;
    WoT[(size_t)n * HID + k] = f2h(Wo[(size_t)k * OUTD + n]);
}

// ---------------- P3: action fp32 -> fp16 (layout preserved) ----------------
__global__ __launch_bounds__(256) void k_prep_act(const float* __restrict__ act,
                                                  u16* __restrict__ acth) {
    int i = (blockIdx.x * 256 + threadIdx.x) * 4;
    float4 v = *(const float4*)(act + i);
    ushort4 h = make_ushort4(f2h(v.x), f2h(v.y), f2h(v.z), f2h(v.w));
    *(ushort4*)(acth + i) = h;
}

// ---------------- h0 partial GEMM (fp32, split-K) ----------------
#define H0_SPLIT 10
#define H0_KC    800
__global__ __launch_bounds__(256) void k_h0(const float* __restrict__ x,
                                            const float* __restrict__ Win,
                                            float* __restrict__ part) {
    __shared__ float As[32][33];   // [k][m]
    __shared__ float Bs[32][68];   // [k][n]
    const int n0 = blockIdx.x * 64, m0 = blockIdx.y * 32, s = blockIdx.z;
    const int tid = threadIdx.x;
    const int tm = tid >> 4, tn = tid & 15;
    float acc[2][4] = {};

    const int ar = tid >> 3, ac4 = (tid & 7) * 4;
    int br[2], bn4[2];
#pragma unroll
    for (int i = 0; i < 2; i++) { int e = tid + 256 * i; br[i] = e >> 4; bn4[i] = (e & 15) * 4; }
    const int k0 = s * H0_KC;

    float4 aReg = *(const float4*)(x + (size_t)(m0 + ar) * KIN + k0 + ac4);
    float4 bReg0 = *(const float4*)(Win + (size_t)(k0 + br[0]) * HID + n0 + bn4[0]);
    float4 bReg1 = *(const float4*)(Win + (size_t)(k0 + br[1]) * HID + n0 + bn4[1]);

    for (int it = 0; it < 25; it++) {
        __syncthreads();
        As[ac4 + 0][ar] = aReg.x; As[ac4 + 1][ar] = aReg.y;
        As[ac4 + 2][ar] = aReg.z; As[ac4 + 3][ar] = aReg.w;
        *(float4*)&Bs[br[0]][bn4[0]] = bReg0;
        *(float4*)&Bs[br[1]][bn4[1]] = bReg1;
        if (it < 24) {
            int kn = k0 + (it + 1) * 32;
            aReg  = *(const float4*)(x + (size_t)(m0 + ar) * KIN + kn + ac4);
            bReg0 = *(const float4*)(Win + (size_t)(kn + br[0]) * HID + n0 + bn4[0]);
            bReg1 = *(const float4*)(Win + (size_t)(kn + br[1]) * HID + n0 + bn4[1]);
        }
        __syncthreads();
#pragma unroll
        for (int kk = 0; kk < 32; kk++) {
            float a0 = As[kk][tm * 2], a1 = As[kk][tm * 2 + 1];
            float4 b = *(float4*)&Bs[kk][tn * 4];
            acc[0][0] = fmaf(a0, b.x, acc[0][0]); acc[0][1] = fmaf(a0, b.y, acc[0][1]);
            acc[0][2] = fmaf(a0, b.z, acc[0][2]); acc[0][3] = fmaf(a0, b.w, acc[0][3]);
            acc[1][0] = fmaf(a1, b.x, acc[1][0]); acc[1][1] = fmaf(a1, b.y, acc[1][1]);
            acc[1][2] = fmaf(a1, b.z, acc[1][2]); acc[1][3] = fmaf(a1, b.w, acc[1][3]);
        }
    }
    float* dst = part + (size_t)s * (BS * HID);
#pragma unroll
    for (int i = 0; i < 2; i++) {
        float4 v = make_float4(acc[i][0], acc[i][1], acc[i][2], acc[i][3]);
        *(float4*)(dst + (size_t)(m0 + tm * 2 + i) * HID + n0 + tn * 4) = v;
    }
}

// reduce partials; write fp32 h0 and fragment-order fp16 h0 into hfrag buf 0.
__global__ __launch_bounds__(256) void k_h0red(const float* __restrict__ part,
                                               const float* __restrict__ b_in,
                                               float* __restrict__ h0,
                                               u16* __restrict__ hfrag) {
    int idx = (blockIdx.x * 256 + threadIdx.x) * 4;
    float4 sv = *(const float4*)(part + idx);
#pragma unroll
    for (int p = 1; p < H0_SPLIT; p++) {
        float4 v = *(const float4*)(part + (size_t)p * (BS * HID) + idx);
        sv.x += v.x; sv.y += v.y; sv.z += v.z; sv.w += v.w;
    }
    int n = idx & (HID - 1);
    float4 b = *(const float4*)(b_in + n);
    sv.x = fmaxf(sv.x + b.x, 0.f); sv.y = fmaxf(sv.y + b.y, 0.f);
    sv.z = fmaxf(sv.z + b.z, 0.f); sv.w = fmaxf(sv.w + b.w, 0.f);
    *(float4*)(h0 + idx) = sv;
    int row = idx >> 10;
    float vv[4] = {sv.x, sv.y, sv.z, sv.w};
#pragma unroll
    for (int i = 0; i < 4; i++) {
        int c = n + i;
        int lane = ((c & 31) >> 3) * 16 + (row & 15);
        size_t off = ((size_t)(row >> 4) * 32 + (c >> 5)) * 512 + lane * 8 + (c & 7);
        __hip_atomic_store(hfrag + off, f2h(vv[i]), __ATOMIC_RELAXED, __HIP_MEMORY_SCOPE_AGENT);
    }
}

// ---- helper pieces for k_gru ----
// R14: data loads are PLAIN CACHED loads (global_load_dwordx4, no sc bits).
// Producers store with agent-scope (sc1, write-through to IC); consumer L2 lines
// for a per-step buffer are cold within a launch (each range read once), and
// dispatch-acquire invalidation across launches is proven by k_out's plain loads
// passing. Plain loads let the ~8 same-group blocks per XCD share L2 lines
// (first reader pulls IC, rest hit L2) instead of every read paying sc1-bypass.
__device__ __forceinline__ void issue8(f16x8* dst, const u16* base, int rgrp,
                                       int kb0, int lane) {
#pragma unroll
    for (int kt = 0; kt < 8; kt++)
        dst[kt] = *(const f16x8*)(const void*)
                  (base + ((size_t)(rgrp * 32 + kb0 + kt) << 9) + lane * 8);
}

__device__ __forceinline__ void mfma_stage(const f16x8* src, const u16* wbr,
                                           const u16* wbz, const u16* wbn,
                                           int kst, int koff, int kq,
                                           f32x4& vR, f32x4& vZ, f32x4& vN, f32x4& vI) {
#pragma unroll
    for (int kt = 0; kt < 8; kt++) {
        const int k = kst + kt * 32;
        f16x8 a = src[kt];
        f16x8 wr = *(const f16x8*)&wbr[k + koff];
        f16x8 wz = *(const f16x8*)&wbz[k + koff];
        f16x8 wn = *(const f16x8*)&wbn[k + koff];
        vR = MFMA16(a, wr, vR);
        vZ = MFMA16(a, wz, vZ);
        vN = MFMA16(a, wn, vN);
    }
    if (kq == 3) {                         // action block, k=1024..1055 (Wi rows)
        f16x8 a = src[8];
        f16x8 wr = *(const f16x8*)&wbr[1024 + koff];
        f16x8 wz = *(const f16x8*)&wbz[1024 + koff];
        f16x8 wn = *(const f16x8*)&wbn[1024 + koff];
        vR = MFMA16(a, wr, vR);
        vZ = MFMA16(a, wz, vZ);
        vI = MFMA16(a, wn, vI);            // i_n kept separate from h_n
    }
}

__device__ __forceinline__ void red_write(float* REDp, int bsup, int kq, int lane,
                                          const f32x4& vR, const f32x4& vZ,
                                          const f32x4& vN, const f32x4& vI) {
    float* d = &REDp[((bsup * 3 + (kq - 1)) * 64 + lane) * 17];
#pragma unroll
    for (int i = 0; i < 4; i++) {
        d[i] = vR[i]; d[4 + i] = vZ[i]; d[8 + i] = vN[i]; d[12 + i] = vI[i];
    }
}

__device__ __forceinline__ void finish_stage(const float* REDp, const f32x4& vR,
                                             const f32x4& vZ, const f32x4& vN,
                                             const f32x4& vI, float bir, float biz,
                                             float bin_, float bh_, float* hreg,
                                             u16* HSTx, int bsup, int lane,
                                             int lh, int j7) {
    float R[4], Z[4], N[4], I[4];
#pragma unroll
    for (int rg = 0; rg < 4; rg++) {
        R[rg] = vR[rg]; Z[rg] = vZ[rg]; N[rg] = vN[rg]; I[rg] = vI[rg];
    }
#pragma unroll
    for (int src = 0; src < 3; src++) {
        const float* d = &REDp[((bsup * 3 + src) * 64 + lane) * 17];
#pragma unroll
        for (int rg = 0; rg < 4; rg++) {
            R[rg] += d[rg]; Z[rg] += d[4 + rg];
            N[rg] += d[8 + rg]; I[rg] += d[12 + rg];
        }
    }
#pragma unroll
    for (int rg = 0; rg < 4; rg++) {
        float r = sigm(R[rg] + bir);
        float z = sigm(Z[rg] + biz);
        float n = tanh_fast(I[rg] + bin_ + r * (N[rg] + bh_));
        float hnew = (1.0f - z) * n + z * hreg[rg];
        hreg[rg] = hnew;
        HSTx[bsup * 256 + (lh + rg) * 8 + j7] = f2h(hnew);
    }
}

// data stores stay agent-scope (sc1): must bypass producer L2 so remote XCDs'
// reads from IC see them.
__device__ __forceinline__ void store_stage(const u16* HSTx, int rgbase, u16* nb,
                                            int jb, int halfbase, int srg, int sq) {
    u64 v = *(const u64*)(const void*)&HSTx[srg * 256 + sq * 4];
    u64* dst = (u64*)(void*)(nb + ((size_t)((rgbase + srg) * 32 + jb) << 9)
                             + halfbase + sq * 4);
    __hip_atomic_store(dst, v, __ATOMIC_RELAXED, __HIP_MEMORY_SCOPE_AGENT);
}

// R14 sync: per-block FLAG ARRAY instead of one shared counter.
// R13's 128 fetch_adds/step to a single address serialize at the coherence
// point (~30-50cy each => ~4-6k cy/step) -- the hidden barrier cost.
// Producer wave lane0 STOREs t+1 into its private slot (no RMW). Consumer
// wave 0 polls: lane l loads the u64 holding producer-block l's two wave
// flags (one coalesced instruction/iteration), __all() across 64 lanes.
__device__ __forceinline__ void pollflags(const u64* f, u32 tgt, int lane) {
    for (u32 it = 0; it < POLL_CAP; ++it) {
        u64 v = __hip_atomic_load(f + lane, __ATOMIC_RELAXED, __HIP_MEMORY_SCOPE_AGENT);
        bool ok = ((u32)v >= tgt) && ((u32)(v >> 32) >= tgt);
        if (__all(ok)) return;
        __builtin_amdgcn_s_sleep(1);
    }
}

// ---------------- persistent GRU: two interleaved half-chains (A/B pipeline) ----------------
// 256 blocks x 512 thr. Block bx: j0=(bx>>2)*16, pair p=bx&3, jt=bx>>2.
// Chain A = rows p*32..+31 (flag group p); chain B = rows 128+p*32.. (group 4+p).
// Schedule identical to R13; only sync mechanics (flags, wave-poll) and data-load
// caching changed.
__global__ __launch_bounds__(512, 1) void k_gru(const float* __restrict__ h0f,
                                                const u16* __restrict__ acth,
                                                const u16* __restrict__ Wf,
                                                const float* __restrict__ bi,
                                                const float* __restrict__ bhn,
                                                u16* __restrict__ hfrag,
                                                u32* __restrict__ bars) {
    __shared__ u16 Wlds[3 * 16 * WP];      // 106 KB
    __shared__ float RED[2 * 3 * 64 * 17]; // 26.1 KB, pitch 17 conflict-free
    __shared__ u16 HSTA[512], HSTB[512];   // 1 KB per stage (2 rgrp x 256 u16)

    const int tid = threadIdx.x;
    const int bx = blockIdx.x;
    const int j0 = (bx >> 2) * 16;
    const int p  = bx & 3;
    const int jt = bx >> 2;                // j-tile index = slot within flag group
    const int w = tid >> 6;
    const int bsup = w >> 2, kq = w & 3;
    const int lane = tid & 63;
    const int m16 = lane & 15, quad = lane >> 4;

    const int kst = kq * 256;
    const int kb0 = kq * 8;
    const int koff = quad * 8;
    const int rgA = p * 2 + bsup;
    const int rgB = 8 + p * 2 + bsup;
    const int rowA = p * 32 + bsup * 16 + m16;
    const int rowB = 128 + rowA;
    const int jb = j0 >> 5;
    const int halfbase = (j0 & 16) ? 256 : 0;
    // flag arrays: group g occupies bars[g*128 .. g*128+127]; block slot = jt*2+wave
    u32* flagA = bars + p * 128;
    u32* flagB = bars + (4 + p) * 128;
    const int srg = tid >> 6, sq = tid & 63;   // store map (tid<128)
    const int j = j0 + m16;
    const int lh = ((j & 15) >> 3) * 16 + quad * 4;
    const int j7 = j & 7;

    // ---- pre-issue chain-A loads for t=0 (buf 0 from k_h0red; no LDS dep) ----
    f16x8 aA[9];
    issue8(aA, hfrag, rgA, kb0, lane);
    if (kq == 3)
        aA[8] = *(const f16x8*)(const void*)(acth + (size_t)rowA * (TST * ACTD) + koff);

    // ---- stage weight slice to LDS (once; overlaps the aloads above) ----
    for (int pp = 0; pp < 13; pp++) {
        int c = tid + pp * 512;                // 6336 chunks of 8 halfs
        if (c < 6336) {
            int row = c / 132, kc = (c % 132) * 8;
            int g = row >> 4, jj = row & 15;
            int4 v = *(const int4*)(const void*)(Wf + (size_t)(g * HID + j0 + jj) * KTOT + kc);
            *(int4*)(void*)&Wlds[row * WP + kc] = v;
        }
    }

    // ---- per-chain persistent state (finisher waves kq==0) ----
    float bir = 0, biz = 0, bin_ = 0, bh_ = 0;
    float hregA[4] = {}, hregB[4] = {};
    if (kq == 0) {
        bir = bi[j]; biz = bi[HID + j]; bin_ = bi[2 * HID + j]; bh_ = bhn[j];
#pragma unroll
        for (int rg = 0; rg < 4; rg++) {
            hregA[rg] = h0f[(size_t)(p * 32 + bsup * 16 + quad * 4 + rg) * HID + j];
            hregB[rg] = h0f[(size_t)(128 + p * 32 + bsup * 16 + quad * 4 + rg) * HID + j];
        }
    }
    __syncthreads();                           // Wlds ready

    const u16* wbr = &Wlds[(0 * 16 + m16) * WP];
    const u16* wbz = &Wlds[(1 * 16 + m16) * WP];
    const u16* wbn = &Wlds[(2 * 16 + m16) * WP];

    for (int t = 0; t < TST; t++) {
        const u16* bufT = hfrag + (size_t)t * HEXCH;
        u16* bufT1 = hfrag + (size_t)(t + 1) * HEXCH;

        // ---- A: MFMA (aA issued one phase earlier) ----
        f32x4 aRv = {0,0,0,0}, aZv = {0,0,0,0}, aNv = {0,0,0,0}, aIv = {0,0,0,0};
        mfma_stage(aA, wbr, wbz, wbn, kst, koff, kq, aRv, aZv, aNv, aIv);
        if (kq != 0) red_write(RED, bsup, kq, lane, aRv, aZv, aNv, aIv);

        // ---- poll B(t) ready (flags from end of iter t-1); doubles as A-RED barrier ----
        if (tid < 64 && t > 0) pollflags((const u64*)flagB, (u32)t, lane);
        __syncthreads();                       // S1

        // ---- issue B loads early (latency hides under A-finish) ----
        f16x8 aB[9];
        issue8(aB, bufT, rgB, kb0, lane);
        if (kq == 3)
            aB[8] = *(const f16x8*)(const void*)(acth + (size_t)rowB * (TST * ACTD)
                                                 + t * ACTD + koff);

        if (kq == 0)
            finish_stage(RED, aRv, aZv, aNv, aIv, bir, biz, bin_, bh_,
                         hregA, HSTA, bsup, lane, lh, j7);
        __syncthreads();                       // S2 (HSTA ready, RED reads done)

        // ---- A-store h_A(t+1) + per-wave flag (waves 0-1; no RMW) ----
        if (tid < 128) {
            store_stage(HSTA, p * 2, bufT1, jb, halfbase, srg, sq);
            __builtin_amdgcn_s_waitcnt(0);     // this wave's data stores acked
            if ((tid & 63) == 0 && t < TST - 1)
                __hip_atomic_store(flagA + jt * 2 + w, (u32)(t + 1),
                                   __ATOMIC_RELAXED, __HIP_MEMORY_SCOPE_AGENT);
        }

        // ---- B: MFMA ----
        f32x4 bRv = {0,0,0,0}, bZv = {0,0,0,0}, bNv = {0,0,0,0}, bIv = {0,0,0,0};
        mfma_stage(aB, wbr, wbz, wbn, kst, koff, kq, bRv, bZv, bNv, bIv);
        if (kq != 0) red_write(RED, bsup, kq, lane, bRv, bZv, bNv, bIv);

        // ---- poll A(t+1) ready (flagged above by all 64 blocks of group p) ----
        if (tid < 64 && t < TST - 1) pollflags((const u64*)flagA, (u32)(t + 1), lane);
        __syncthreads();                       // S3

        // ---- issue A(t+1) loads (waves 2-7 now; waves 0-1 after their B-store) ----
        if (t < TST - 1 && w >= 2) {
            issue8(aA, bufT1, rgA, kb0, lane);
            if (kq == 3)
                aA[8] = *(const f16x8*)(const void*)(acth + (size_t)rowA * (TST * ACTD)
                                                     + (t + 1) * ACTD + koff);
        }

        if (kq == 0)
            finish_stage(RED, bRv, bZv, bNv, bIv, bir, biz, bin_, bh_,
                         hregB, HSTB, bsup, lane, lh, j7);
        __syncthreads();                       // S4

        // ---- B-store h_B(t+1) + per-wave flag ----
        if (tid < 128) {
            store_stage(HSTB, 8 + p * 2, bufT1, jb, halfbase, srg, sq);
            __builtin_amdgcn_s_waitcnt(0);
            if ((tid & 63) == 0 && t < TST - 1)
                __hip_atomic_store(flagB + jt * 2 + w, (u32)(t + 1),
                                   __ATOMIC_RELAXED, __HIP_MEMORY_SCOPE_AGENT);
        }
        if (t < TST - 1 && w < 2)              // w<2 has kq in {0,1}: no action load
            issue8(aA, bufT1, rgA, kb0, lane);
        // last step: stores drain at kernel end; k_out acquires at launch.
    }
}

// ---------------- k_out: out[b][t][:] = h_{t+1}[b] @ Wo + bo ----------------
// A comes straight from the fragment-order h buffers: chunk (t+1, rgrp, kb)
// holds the exact MFMA A-fragment (lane = kq*16 + row, 8 k-elems). No LDS.
__global__ __launch_bounds__(256) void k_out(const u16* __restrict__ hfrag,
                                             const u16* __restrict__ WoT,
                                             const float* __restrict__ bo,
                                             float* __restrict__ out) {
    const int tid = threadIdx.x;
    const int t = blockIdx.x % TST;            // 0..99
    const int rg4 = blockIdx.x / TST;          // 0..3
    const int w = tid >> 6, lane = tid & 63;
    const int m16 = lane & 15, quad = lane >> 4;
    const int rgrp = rg4 * 4 + w;              // 0..15 (16 batch rows each)

    const u16* abase = hfrag + (size_t)(t + 1) * HEXCH
                     + (((size_t)rgrp * 32) << 9) + lane * 8;
    const u16* bbase = WoT + (size_t)m16 * HID + quad * 8;
    f32x4 acc[4] = {{0,0,0,0},{0,0,0,0},{0,0,0,0},{0,0,0,0}};

#pragma unroll 4
    for (int kb = 0; kb < 32; kb++) {
        f16x8 a = *(const f16x8*)(const void*)(abase + (kb << 9));
        const u16* bp = bbase + kb * 32;
#pragma unroll
        for (int nt = 0; nt < 4; nt++) {
            f16x8 b = *(const f16x8*)(const void*)(bp + (size_t)nt * 16 * HID);
            acc[nt] = __builtin_amdgcn_mfma_f32_16x16x32_f16(a, b, acc[nt], 0, 0, 0);
        }
    }
    const int brow = rgrp * 16 + quad * 4;     // C layout: col=lane&15, row=quad*4+reg
#pragma unroll
    for (int nt = 0; nt < 4; nt++) {
        int n = nt * 16 + m16;
        float bov = bo[n];
#pragma unroll
        for (int rg = 0; rg < 4; rg++) {
            int b = brow + rg;
            out[((size_t)b * TST + t) * OUTD + n] = acc[nt][rg] + bov;
        }
    }
}

extern "C" void kernel_launch(void* const* d_in, const int* in_sizes, int n_in,
                              void* d_out, int out_size, void* d_ws, size_t ws_size,
                              hipStream_t stream) {
    const float* history = (const float*)d_in[0];
    const float* action  = (const float*)d_in[1];
    const float* W_in    = (const float*)d_in[2];
    const float* b_in    = (const float*)d_in[3];
    const float* Wi      = (const float*)d_in[4];
    const float* bi      = (const float*)d_in[5];
    const float* Wh      = (const float*)d_in[6];
    const float* bhn     = (const float*)d_in[7];
    const float* Wo      = (const float*)d_in[8];
    const float* bo      = (const float*)d_in[9];
    float* out = (float*)d_out;

    char* ws = (char*)d_ws;
    float* hbuf0 = (float*)(ws + 0);                    // 1 MB (fp32 h0)
    u16*   Wf    = (u16*)  (ws + (3u << 20));           // 6.33 MB
    u16*   WoT   = (u16*)  (ws + (10u << 20));          // 128 KB
    u16*   acth  = (u16*)  (ws + (11u << 20));          // 1.6 MB
    float* part  = (float*)(ws + (13u << 20));          // 10 MB (13..23 MiB)
    u32*   bars  = (u32*)  (ws + (23u << 20));          // 4 KB: 8 groups x 128 flags
    u16*   hfrag = (u16*)  (ws + (24u << 20));          // 101 x 512 KB = 50.5 MB

    (void)hipMemsetAsync(bars, 0, 4096, stream);        // flags must reset EVERY launch
    k_prep_w<<<dim3(33, 96), 256, 0, stream>>>(Wh, Wi, Wf);
    k_prep_wo<<<256, 256, 0, stream>>>(Wo, WoT);
    k_prep_act<<<800, 256, 0, stream>>>(action, acth);
    k_h0<<<dim3(16, 8, H0_SPLIT), 256, 0, stream>>>(history, W_in, part);
    k_h0red<<<256, 256, 0, stream>>>(part, b_in, hbuf0, hfrag);

    {
        const float* a0 = hbuf0; const u16* a1 = acth; const u16* a2 = Wf;
        const float* a3 = bi;    const float* a4 = bhn;
        u16* a5 = hfrag;         u32* a6 = bars;
        void* args[] = {(void*)&a0, (void*)&a1, (void*)&a2, (void*)&a3,
                        (void*)&a4, (void*)&a5, (void*)&a6};
        (void)hipLaunchCooperativeKernel((const void*)k_gru, dim3(256), dim3(512),
                                         args, 0, stream);
    }

    k_out<<<dim3(400), 256, 0, stream>>>(hfrag, WoT, bo, out);
}

// Round 8
// 699.012 us; speedup vs baseline: 2.0260x; 1.0413x over previous
//
#include <hip/hip_runtime.h>

#define BS   256
#define HID  1024
#define KIN  8000
#define TST  100
#define ACTD 32
#define OUTD 64
#define KTOT 1056            // 1024 (Wh) + 32 (Wi) concatenated K
#define WP   1104            // Wlds row pitch in halfs (552 dw, %32==8 -> uniform banks)
#define HEXCH (16 * 32 * 512)  // one h buffer: 16 rgrp x 32 kb x 512 u16 (512 KB)
#define POLL_CAP (1u << 18)    // bounded spin: protocol bug -> wrong result, NOT a hang

typedef __attribute__((ext_vector_type(8))) _Float16 f16x8;
typedef __attribute__((ext_vector_type(4))) float f32x4;
typedef unsigned short u16;
typedef unsigned int   u32;
typedef unsigned long long u64;

__device__ __forceinline__ u16 f2h(float f) {
    union { _Float16 h; u16 u; } c;
    c.h = (_Float16)f;             // v_cvt_f16_f32, RNE
    return c.u;
}
// fast sigmoid/tanh: v_exp + v_rcp. tanh via -2|x| (exp underflows, never NaN).
__device__ __forceinline__ float sigm(float x) {
    return __builtin_amdgcn_rcpf(1.0f + __expf(-x));
}
__device__ __forceinline__ float tanh_fast(float x) {
    float e = __expf(-2.0f * fabsf(x));
    float t = (1.0f - e) * __builtin_amdgcn_rcpf(1.0f + e);
    return copysignf(t, x);
}

#define MFMA16(a, b, c) __builtin_amdgcn_mfma_f32_16x16x32_f16(a, b, c, 0, 0, 0)

// ---------------- P1: WfT[c][k] = fp16(Wh[k][c] | Wi[k-1024][c]) ----------------
__global__ __launch_bounds__(256) void k_prep_w(const float* __restrict__ Wh,
                                                const float* __restrict__ Wi,
                                                u16* __restrict__ Wf) {
    __shared__ float T[32][33];
    const int k0 = blockIdx.x * 32;      // 33 tiles cover k=0..1055
    const int c0 = blockIdx.y * 32;
    const int tid = threadIdx.x;
    {
        int k = tid >> 3, c4 = (tid & 7) * 4;
        int kk = k0 + k;
        const float* src = (kk < HID) ? (Wh + (size_t)kk * 3072 + c0 + c4)
                                      : (Wi + (size_t)(kk - HID) * 3072 + c0 + c4);
        float4 v = *(const float4*)src;
        T[k][c4 + 0] = v.x; T[k][c4 + 1] = v.y; T[k][c4 + 2] = v.z; T[k][c4 + 3] = v.w;
    }
    __syncthreads();
    {
        int c = tid >> 3, k4 = (tid & 7) * 4;
        size_t base = (size_t)(c0 + c) * KTOT + k0 + k4;
#pragma unroll
        for (int j = 0; j < 4; j++) Wf[base + j] = f2h(T[k4 + j][c]);
    }
}

// ---------------- P2: WoT[n][k] = fp16(Wo[k][n]) ----------------
__global__ __launch_bounds__(256) void k_prep_wo(const float* __restrict__ Wo,
                                                 u16* __restrict__ WoT) {
    int idx = blockIdx.x * 256 + threadIdx.x;   // 65536
    int n = idx & 63, k = idx >> 6;
    WoT[(size_t)n * HID + k] = f2h(Wo[(size_t)k * OUTD + n]);
}

// ---------------- P3: action fp32 -> fp16 (layout preserved) ----------------
__global__ __launch_bounds__(256) void k_prep_act(const float* __restrict__ act,
                                                  u16* __restrict__ acth) {
    int i = (blockIdx.x * 256 + threadIdx.x) * 4;
    float4 v = *(const float4*)(act + i);
    ushort4 h = make_ushort4(f2h(v.x), f2h(v.y), f2h(v.z), f2h(v.w));
    *(ushort4*)(acth + i) = h;
}

// ---------------- h0 partial GEMM (fp32, split-K) ----------------
#define H0_SPLIT 10
#define H0_KC    800
__global__ __launch_bounds__(256) void k_h0(const float* __restrict__ x,
                                            const float* __restrict__ Win,
                                            float* __restrict__ part) {
    __shared__ float As[32][33];   // [k][m]
    __shared__ float Bs[32][68];   // [k][n]
    const int n0 = blockIdx.x * 64, m0 = blockIdx.y * 32, s = blockIdx.z;
    const int tid = threadIdx.x;
    const int tm = tid >> 4, tn = tid & 15;
    float acc[2][4] = {};

    const int ar = tid >> 3, ac4 = (tid & 7) * 4;
    int br[2], bn4[2];
#pragma unroll
    for (int i = 0; i < 2; i++) { int e = tid + 256 * i; br[i] = e >> 4; bn4[i] = (e & 15) * 4; }
    const int k0 = s * H0_KC;

    float4 aReg = *(const float4*)(x + (size_t)(m0 + ar) * KIN + k0 + ac4);
    float4 bReg0 = *(const float4*)(Win + (size_t)(k0 + br[0]) * HID + n0 + bn4[0]);
    float4 bReg1 = *(const float4*)(Win + (size_t)(k0 + br[1]) * HID + n0 + bn4[1]);

    for (int it = 0; it < 25; it++) {
        __syncthreads();
        As[ac4 + 0][ar] = aReg.x; As[ac4 + 1][ar] = aReg.y;
        As[ac4 + 2][ar] = aReg.z; As[ac4 + 3][ar] = aReg.w;
        *(float4*)&Bs[br[0]][bn4[0]] = bReg0;
        *(float4*)&Bs[br[1]][bn4[1]] = bReg1;
        if (it < 24) {
            int kn = k0 + (it + 1) * 32;
            aReg  = *(const float4*)(x + (size_t)(m0 + ar) * KIN + kn + ac4);
            bReg0 = *(const float4*)(Win + (size_t)(kn + br[0]) * HID + n0 + bn4[0]);
            bReg1 = *(const float4*)(Win + (size_t)(kn + br[1]) * HID + n0 + bn4[1]);
        }
        __syncthreads();
#pragma unroll
        for (int kk = 0; kk < 32; kk++) {
            float a0 = As[kk][tm * 2], a1 = As[kk][tm * 2 + 1];
            float4 b = *(float4*)&Bs[kk][tn * 4];
            acc[0][0] = fmaf(a0, b.x, acc[0][0]); acc[0][1] = fmaf(a0, b.y, acc[0][1]);
            acc[0][2] = fmaf(a0, b.z, acc[0][2]); acc[0][3] = fmaf(a0, b.w, acc[0][3]);
            acc[1][0] = fmaf(a1, b.x, acc[1][0]); acc[1][1] = fmaf(a1, b.y, acc[1][1]);
            acc[1][2] = fmaf(a1, b.z, acc[1][2]); acc[1][3] = fmaf(a1, b.w, acc[1][3]);
        }
    }
    float* dst = part + (size_t)s * (BS * HID);
#pragma unroll
    for (int i = 0; i < 2; i++) {
        float4 v = make_float4(acc[i][0], acc[i][1], acc[i][2], acc[i][3]);
        *(float4*)(dst + (size_t)(m0 + tm * 2 + i) * HID + n0 + tn * 4) = v;
    }
}

// reduce partials; write fp32 h0 and fragment-order fp16 h0 into hfrag buf 0.
__global__ __launch_bounds__(256) void k_h0red(const float* __restrict__ part,
                                               const float* __restrict__ b_in,
                                               float* __restrict__ h0,
                                               u16* __restrict__ hfrag) {
    int idx = (blockIdx.x * 256 + threadIdx.x) * 4;
    float4 sv = *(const float4*)(part + idx);
#pragma unroll
    for (int p = 1; p < H0_SPLIT; p++) {
        float4 v = *(const float4*)(part + (size_t)p * (BS * HID) + idx);
        sv.x += v.x; sv.y += v.y; sv.z += v.z; sv.w += v.w;
    }
    int n = idx & (HID - 1);
    float4 b = *(const float4*)(b_in + n);
    sv.x = fmaxf(sv.x + b.x, 0.f); sv.y = fmaxf(sv.y + b.y, 0.f);
    sv.z = fmaxf(sv.z + b.z, 0.f); sv.w = fmaxf(sv.w + b.w, 0.f);
    *(float4*)(h0 + idx) = sv;
    int row = idx >> 10;
    float vv[4] = {sv.x, sv.y, sv.z, sv.w};
#pragma unroll
    for (int i = 0; i < 4; i++) {
        int c = n + i;
        int lane = ((c & 31) >> 3) * 16 + (row & 15);
        size_t off = ((size_t)(row >> 4) * 32 + (c >> 5)) * 512 + lane * 8 + (c & 7);
        __hip_atomic_store(hfrag + off, f2h(vv[i]), __ATOMIC_RELAXED, __HIP_MEMORY_SCOPE_AGENT);
    }
}

// ---- helper pieces for k_gru (R14-proven mechanics, unchanged) ----
// Plain cached consumer loads (R14-proven: per-step buffers are first-touch,
// producers store agent-scope, dispatch/flag ordering covers visibility).
__device__ __forceinline__ void issue8(f16x8* dst, const u16* base, int rgrp,
                                       int kb0, int lane) {
#pragma unroll
    for (int kt = 0; kt < 8; kt++)
        dst[kt] = *(const f16x8*)(const void*)
                  (base + ((size_t)(rgrp * 32 + kb0 + kt) << 9) + lane * 8);
}

__device__ __forceinline__ void mfma_stage(const f16x8* src, const u16* wbr,
                                           const u16* wbz, const u16* wbn,
                                           int kst, int koff, int kq,
                                           f32x4& vR, f32x4& vZ, f32x4& vN, f32x4& vI) {
#pragma unroll
    for (int kt = 0; kt < 8; kt++) {
        const int k = kst + kt * 32;
        f16x8 a = src[kt];
        f16x8 wr = *(const f16x8*)&wbr[k + koff];
        f16x8 wz = *(const f16x8*)&wbz[k + koff];
        f16x8 wn = *(const f16x8*)&wbn[k + koff];
        vR = MFMA16(a, wr, vR);
        vZ = MFMA16(a, wz, vZ);
        vN = MFMA16(a, wn, vN);
    }
    if (kq == 3) {                         // action block, k=1024..1055 (Wi rows)
        f16x8 a = src[8];
        f16x8 wr = *(const f16x8*)&wbr[1024 + koff];
        f16x8 wz = *(const f16x8*)&wbz[1024 + koff];
        f16x8 wn = *(const f16x8*)&wbn[1024 + koff];
        vR = MFMA16(a, wr, vR);
        vZ = MFMA16(a, wz, vZ);
        vI = MFMA16(a, wn, vI);            // i_n kept separate from h_n
    }
}

__device__ __forceinline__ void red_write(float* REDp, int bsup, int kq, int lane,
                                          const f32x4& vR, const f32x4& vZ,
                                          const f32x4& vN, const f32x4& vI) {
    float* d = &REDp[((bsup * 3 + (kq - 1)) * 64 + lane) * 17];
#pragma unroll
    for (int i = 0; i < 4; i++) {
        d[i] = vR[i]; d[4 + i] = vZ[i]; d[8 + i] = vN[i]; d[12 + i] = vI[i];
    }
}

__device__ __forceinline__ void finish_stage(const float* REDp, const f32x4& vR,
                                             const f32x4& vZ, const f32x4& vN,
                                             const f32x4& vI, float bir, float biz,
                                             float bin_, float bh_, float* hreg,
                                             u16* HSTx, int bsup, int lane,
                                             int lh, int j7) {
    float R[4], Z[4], N[4], I[4];
#pragma unroll
    for (int rg = 0; rg < 4; rg++) {
        R[rg] = vR[rg]; Z[rg] = vZ[rg]; N[rg] = vN[rg]; I[rg] = vI[rg];
    }
#pragma unroll
    for (int src = 0; src < 3; src++) {
        const float* d = &REDp[((bsup * 3 + src) * 64 + lane) * 17];
#pragma unroll
        for (int rg = 0; rg < 4; rg++) {
            R[rg] += d[rg]; Z[rg] += d[4 + rg];
            N[rg] += d[8 + rg]; I[rg] += d[12 + rg];
        }
    }
#pragma unroll
    for (int rg = 0; rg < 4; rg++) {
        float r = sigm(R[rg] + bir);
        float z = sigm(Z[rg] + biz);
        float n = tanh_fast(I[rg] + bin_ + r * (N[rg] + bh_));
        float hnew = (1.0f - z) * n + z * hreg[rg];
        hreg[rg] = hnew;
        HSTx[bsup * 256 + (lh + rg) * 8 + j7] = f2h(hnew);
    }
}

// data stores stay agent-scope (sc1): remote XCDs read via IC.
__device__ __forceinline__ void store_stage(const u16* HSTx, int rgbase, u16* nb,
                                            int jb, int halfbase, int srg, int sq) {
    u64 v = *(const u64*)(const void*)&HSTx[srg * 256 + sq * 4];
    u64* dst = (u64*)(void*)(nb + ((size_t)((rgbase + srg) * 32 + jb) << 9)
                             + halfbase + sq * 4);
    __hip_atomic_store(dst, v, __ATOMIC_RELAXED, __HIP_MEMORY_SCOPE_AGENT);
}

// per-block flag array signal (R14-proven: no RMW serialization);
// consumer wave polls 64 producer slots with one coalesced load per iteration.
__device__ __forceinline__ void pollflags(const u64* f, u32 tgt, int lane) {
    for (u32 it = 0; it < POLL_CAP; ++it) {
        u64 v = __hip_atomic_load(f + lane, __ATOMIC_RELAXED, __HIP_MEMORY_SCOPE_AGENT);
        bool ok = ((u32)v >= tgt) && ((u32)(v >> 32) >= tgt);
        if (__all(ok)) return;
        __builtin_amdgcn_s_sleep(1);
    }
}

// ---------------- persistent GRU: two interleaved half-chains (A/B pipeline) ----------------
// 256 blocks x 512 thr. Block bx: j0=(bx>>2)*16, pair p=bx&3, jt=bx>>2.
// Chain A = rows p*32..+31 (flag group p); chain B = rows 128+p*32.. (group 4+p).
// R17 = R14 (proven @510us) + two safe deltas:
//  (a) poll A(t+1) moved from serial (pre-S3) into wave 2, CONCURRENT with
//      finishB -- wave 2 (kq2) has no finish/store duty and idles there. aA(t+1)
//      issue for w>=2 moves after S4 (stronger barrier; poll guaranteed done).
//  (b) s_setprio(1) around MFMA phases (role-diverse schedule: T5 regime).
// R15/R16's wave-specialized no-barrier variants produced NaN / stale races --
// shelved; __syncthreads here is the proven fence.
__global__ __launch_bounds__(512, 1) void k_gru(const float* __restrict__ h0f,
                                                const u16* __restrict__ acth,
                                                const u16* __restrict__ Wf,
                                                const float* __restrict__ bi,
                                                const float* __restrict__ bhn,
                                                u16* __restrict__ hfrag,
                                                u32* __restrict__ bars) {
    __shared__ u16 Wlds[3 * 16 * WP];      // 106 KB
    __shared__ float RED[2 * 3 * 64 * 17]; // 26.1 KB, pitch 17 conflict-free
    __shared__ u16 HSTA[512], HSTB[512];   // 1 KB per stage (2 rgrp x 256 u16)

    const int tid = threadIdx.x;
    const int bx = blockIdx.x;
    const int j0 = (bx >> 2) * 16;
    const int p  = bx & 3;
    const int jt = bx >> 2;                // slot within flag group
    const int w = tid >> 6;
    const int bsup = w >> 2, kq = w & 3;
    const int lane = tid & 63;
    const int m16 = lane & 15, quad = lane >> 4;

    const int kst = kq * 256;
    const int kb0 = kq * 8;
    const int koff = quad * 8;
    const int rgA = p * 2 + bsup;
    const int rgB = 8 + p * 2 + bsup;
    const int rowA = p * 32 + bsup * 16 + m16;
    const int rowB = 128 + rowA;
    const int jb = j0 >> 5;
    const int halfbase = (j0 & 16) ? 256 : 0;
    // flag arrays: group g occupies bars[g*128 .. g*128+127]; block slot = jt*2+wave
    u32* flagA = bars + p * 128;
    u32* flagB = bars + (4 + p) * 128;
    const int srg = tid >> 6, sq = tid & 63;   // store map (tid<128)
    const int j = j0 + m16;
    const int lh = ((j & 15) >> 3) * 16 + quad * 4;
    const int j7 = j & 7;

    // ---- pre-issue chain-A loads for t=0 (buf 0 from k_h0red; no LDS dep) ----
    f16x8 aA[9];
    issue8(aA, hfrag, rgA, kb0, lane);
    if (kq == 3)
        aA[8] = *(const f16x8*)(const void*)(acth + (size_t)rowA * (TST * ACTD) + koff);

    // ---- stage weight slice to LDS (once; overlaps the loads above) ----
    for (int pp = 0; pp < 13; pp++) {
        int c = tid + pp * 512;                // 6336 chunks of 8 halfs
        if (c < 6336) {
            int row = c / 132, kc = (c % 132) * 8;
            int g = row >> 4, jj = row & 15;
            int4 v = *(const int4*)(const void*)(Wf + (size_t)(g * HID + j0 + jj) * KTOT + kc);
            *(int4*)(void*)&Wlds[row * WP + kc] = v;
        }
    }

    // ---- per-chain persistent state (finisher waves kq==0) ----
    float bir = 0, biz = 0, bin_ = 0, bh_ = 0;
    float hregA[4] = {}, hregB[4] = {};
    if (kq == 0) {
        bir = bi[j]; biz = bi[HID + j]; bin_ = bi[2 * HID + j]; bh_ = bhn[j];
#pragma unroll
        for (int rg = 0; rg < 4; rg++) {
            hregA[rg] = h0f[(size_t)(p * 32 + bsup * 16 + quad * 4 + rg) * HID + j];
            hregB[rg] = h0f[(size_t)(128 + p * 32 + bsup * 16 + quad * 4 + rg) * HID + j];
        }
    }
    __syncthreads();                           // Wlds ready

    const u16* wbr = &Wlds[(0 * 16 + m16) * WP];
    const u16* wbz = &Wlds[(1 * 16 + m16) * WP];
    const u16* wbn = &Wlds[(2 * 16 + m16) * WP];

    for (int t = 0; t < TST; t++) {
        const u16* bufT = hfrag + (size_t)t * HEXCH;
        u16* bufT1 = hfrag + (size_t)(t + 1) * HEXCH;

        // ---- A: MFMA (aA issued one phase earlier) ----
        f32x4 aRv = {0,0,0,0}, aZv = {0,0,0,0}, aNv = {0,0,0,0}, aIv = {0,0,0,0};
        __builtin_amdgcn_s_setprio(1);
        mfma_stage(aA, wbr, wbz, wbn, kst, koff, kq, aRv, aZv, aNv, aIv);
        __builtin_amdgcn_s_setprio(0);
        if (kq != 0) red_write(RED, bsup, kq, lane, aRv, aZv, aNv, aIv);

        // ---- poll B(t) ready (flags from end of iter t-1); doubles as A-RED barrier ----
        if (tid < 64 && t > 0) pollflags((const u64*)flagB, (u32)t, lane);
        __syncthreads();                       // S1

        // ---- issue B loads early (latency hides under A-finish) ----
        f16x8 aB[9];
        issue8(aB, bufT, rgB, kb0, lane);
        if (kq == 3)
            aB[8] = *(const f16x8*)(const void*)(acth + (size_t)rowB * (TST * ACTD)
                                                 + t * ACTD + koff);

        if (kq == 0)
            finish_stage(RED, aRv, aZv, aNv, aIv, bir, biz, bin_, bh_,
                         hregA, HSTA, bsup, lane, lh, j7);
        __syncthreads();                       // S2 (HSTA ready, RED reads done)

        // ---- A-store h_A(t+1) + per-wave flag (waves 0-1; no RMW) ----
        if (tid < 128) {
            store_stage(HSTA, p * 2, bufT1, jb, halfbase, srg, sq);
            __builtin_amdgcn_s_waitcnt(0);     // this wave's data stores acked
            if ((tid & 63) == 0 && t < TST - 1)
                __hip_atomic_store(flagA + jt * 2 + w, (u32)(t + 1),
                                   __ATOMIC_RELAXED, __HIP_MEMORY_SCOPE_AGENT);
        }

        // ---- B: MFMA ----
        f32x4 bRv = {0,0,0,0}, bZv = {0,0,0,0}, bNv = {0,0,0,0}, bIv = {0,0,0,0};
        __builtin_amdgcn_s_setprio(1);
        mfma_stage(aB, wbr, wbz, wbn, kst, koff, kq, bRv, bZv, bNv, bIv);
        __builtin_amdgcn_s_setprio(0);
        if (kq != 0) red_write(RED, bsup, kq, lane, bRv, bZv, bNv, bIv);

        __syncthreads();                       // S3 (REDB ready)

        // ---- finishB CONCURRENT with poll A(t+1) (wave 2: kq2, no finish/store) ----
        if (kq == 0) {
            finish_stage(RED, bRv, bZv, bNv, bIv, bir, biz, bin_, bh_,
                         hregB, HSTB, bsup, lane, lh, j7);
        } else if (w == 2 && t < TST - 1) {
            pollflags((const u64*)flagA, (u32)(t + 1), lane);
        }
        __syncthreads();                       // S4 (HSTB ready + A(t+1) globally ready)

        // ---- issue A(t+1) loads (waves 2-7 now; waves 0-1 after their B-store) ----
        if (t < TST - 1 && w >= 2) {
            issue8(aA, bufT1, rgA, kb0, lane);
            if (kq == 3)
                aA[8] = *(const f16x8*)(const void*)(acth + (size_t)rowA * (TST * ACTD)
                                                     + (t + 1) * ACTD + koff);
        }

        // ---- B-store h_B(t+1) + per-wave flag ----
        if (tid < 128) {
            store_stage(HSTB, 8 + p * 2, bufT1, jb, halfbase, srg, sq);
            __builtin_amdgcn_s_waitcnt(0);
            if ((tid & 63) == 0 && t < TST - 1)
                __hip_atomic_store(flagB + jt * 2 + w, (u32)(t + 1),
                                   __ATOMIC_RELAXED, __HIP_MEMORY_SCOPE_AGENT);
        }
        if (t < TST - 1 && w < 2)              // w<2 has kq in {0,1}: no action load
            issue8(aA, bufT1, rgA, kb0, lane);
        // last step: stores drain at kernel end; k_out acquires at launch.
    }
}

// ---------------- k_out: out[b][t][:] = h_{t+1}[b] @ Wo + bo ----------------
// A comes straight from the fragment-order h buffers: chunk (t+1, rgrp, kb)
// holds the exact MFMA A-fragment (lane = kq*16 + row, 8 k-elems). No LDS.
__global__ __launch_bounds__(256) void k_out(const u16* __restrict__ hfrag,
                                             const u16* __restrict__ WoT,
                                             const float* __restrict__ bo,
                                             float* __restrict__ out) {
    const int tid = threadIdx.x;
    const int t = blockIdx.x % TST;            // 0..99
    const int rg4 = blockIdx.x / TST;          // 0..3
    const int w = tid >> 6, lane = tid & 63;
    const int m16 = lane & 15, quad = lane >> 4;
    const int rgrp = rg4 * 4 + w;              // 0..15 (16 batch rows each)

    const u16* abase = hfrag + (size_t)(t + 1) * HEXCH
                     + (((size_t)rgrp * 32) << 9) + lane * 8;
    const u16* bbase = WoT + (size_t)m16 * HID + quad * 8;
    f32x4 acc[4] = {{0,0,0,0},{0,0,0,0},{0,0,0,0},{0,0,0,0}};

#pragma unroll 4
    for (int kb = 0; kb < 32; kb++) {
        f16x8 a = *(const f16x8*)(const void*)(abase + (kb << 9));
        const u16* bp = bbase + kb * 32;
#pragma unroll
        for (int nt = 0; nt < 4; nt++) {
            f16x8 b = *(const f16x8*)(const void*)(bp + (size_t)nt * 16 * HID);
            acc[nt] = __builtin_amdgcn_mfma_f32_16x16x32_f16(a, b, acc[nt], 0, 0, 0);
        }
    }
    const int brow = rgrp * 16 + quad * 4;     // C layout: col=lane&15, row=quad*4+reg
#pragma unroll
    for (int nt = 0; nt < 4; nt++) {
        int n = nt * 16 + m16;
        float bov = bo[n];
#pragma unroll
        for (int rg = 0; rg < 4; rg++) {
            int b = brow + rg;
            out[((size_t)b * TST + t) * OUTD + n] = acc[nt][rg] + bov;
        }
    }
}

extern "C" void kernel_launch(void* const* d_in, const int* in_sizes, int n_in,
                              void* d_out, int out_size, void* d_ws, size_t ws_size,
                              hipStream_t stream) {
    const float* history = (const float*)d_in[0];
    const float* action  = (const float*)d_in[1];
    const float* W_in    = (const float*)d_in[2];
    const float* b_in    = (const float*)d_in[3];
    const float* Wi      = (const float*)d_in[4];
    const float* bi      = (const float*)d_in[5];
    const float* Wh      = (const float*)d_in[6];
    const float* bhn     = (const float*)d_in[7];
    const float* Wo      = (const float*)d_in[8];
    const float* bo      = (const float*)d_in[9];
    float* out = (float*)d_out;

    char* ws = (char*)d_ws;
    float* hbuf0 = (float*)(ws + 0);                    // 1 MB (fp32 h0)
    u16*   Wf    = (u16*)  (ws + (3u << 20));           // 6.33 MB
    u16*   WoT   = (u16*)  (ws + (10u << 20));          // 128 KB
    u16*   acth  = (u16*)  (ws + (11u << 20));          // 1.6 MB
    float* part  = (float*)(ws + (13u << 20));          // 10 MB (13..23 MiB)
    u32*   bars  = (u32*)  (ws + (23u << 20));          // 4 KB: 8 groups x 128 flags
    u16*   hfrag = (u16*)  (ws + (24u << 20));          // 101 x 512 KB = 50.5 MB

    (void)hipMemsetAsync(bars, 0, 4096, stream);        // flags reset EVERY launch
    k_prep_w<<<dim3(33, 96), 256, 0, stream>>>(Wh, Wi, Wf);
    k_prep_wo<<<256, 256, 0, stream>>>(Wo, WoT);
    k_prep_act<<<800, 256, 0, stream>>>(action, acth);
    k_h0<<<dim3(16, 8, H0_SPLIT), 256, 0, stream>>>(history, W_in, part);
    k_h0red<<<256, 256, 0, stream>>>(part, b_in, hbuf0, hfrag);

    {
        const float* a0 = hbuf0; const u16* a1 = acth; const u16* a2 = Wf;
        const float* a3 = bi;    const float* a4 = bhn;
        u16* a5 = hfrag;         u32* a6 = bars;
        void* args[] = {(void*)&a0, (void*)&a1, (void*)&a2, (void*)&a3,
                        (void*)&a4, (void*)&a5, (void*)&a6};
        (void)hipLaunchCooperativeKernel((const void*)k_gru, dim3(256), dim3(512),
                                         args, 0, stream);
    }

    k_out<<<dim3(400), 256, 0, stream>>>(hfrag, WoT, bo, out);
}